// Round 3
// baseline (461.912 us; speedup 1.0000x reference)
//
#include <hip/hip_runtime.h>

// GCN: 3x gcn_conv + mean-pool + linear, bf16 MFMA pipeline, fused layers.
// out[i] = dinv[i] * (sum_{e: dst=i} g[src_e] + g[i]) + b,  g = dinv .* (x @ W)
// Structure: k0 zero -> k1 prep(conv_x+weights+count) -> scan1 -> scan23
//   -> k4 gemm1 (fill_csr EMBEDDED per-thread, hidden under K-loop)
//   -> k5 agg1+gemm2 (fused, LDS A-tile) -> k6 agg2+gemm3 -> agg3 -> pool -> final.

typedef __attribute__((ext_vector_type(8))) short short8_t;
typedef __attribute__((ext_vector_type(4))) float float4_t;

__device__ __forceinline__ unsigned short f2bf(float f) {
    unsigned int u = __float_as_uint(f);
    u += 0x7FFFu + ((u >> 16) & 1u);   // round-to-nearest-even
    return (unsigned short)(u >> 16);
}
__device__ __forceinline__ float bf2f(unsigned short h) {
    return __uint_as_float(((unsigned int)h) << 16);
}

// async global->LDS, 16B per lane; LDS dest is wave-uniform base + lane*16
#define GLDS16(gp, lp)                                                          \
    __builtin_amdgcn_global_load_lds(                                           \
        (const __attribute__((address_space(1))) void*)(gp),                    \
        (__attribute__((address_space(3))) void*)(lp), 16, 0, 0)

template <int DWN> struct VecT;
template <> struct VecT<2> { using type = uint2; };
template <> struct VecT<4> { using type = uint4; };

// ---------------- k0: zero indeg + sums + cnt ----------------
__global__ void zero_k(int* __restrict__ p, int n) {
    int i = blockIdx.x * blockDim.x + threadIdx.x;
    if (i < n) p[i] = 0;
}

// ---------------- k1: conv_x + weight transpose + count_indeg ----------------
__global__ __launch_bounds__(256) void prep(const float* __restrict__ x,
                                            ushort* __restrict__ Xb,
                                            const float* __restrict__ W1, ushort* __restrict__ Wt1,
                                            const float* __restrict__ W2, ushort* __restrict__ Wt2,
                                            const float* __restrict__ W3, ushort* __restrict__ Wt3,
                                            const int* __restrict__ dst, int* __restrict__ indeg,
                                            int M, int Mpad, int E, int nxblk) {
    int bx = blockIdx.x;
    if (bx < nxblk) {                        // conv_x: fp32 x -> bf16 Xb (padded)
        int t = bx * 256 + threadIdx.x;      // one float4 -> ushort4
        int row = t >> 7;
        ushort4 o;
        if (row < M) {
            float4 v = ((const float4*)x)[t];
            o.x = f2bf(v.x); o.y = f2bf(v.y); o.z = f2bf(v.z); o.w = f2bf(v.w);
        } else {
            o.x = o.y = o.z = o.w = 0;
        }
        if (row < Mpad) ((ushort4*)Xb)[t] = o;
    } else if (bx < nxblk + 672) {           // weight transpose+convert (672*256 = 172032)
        int t = (bx - nxblk) * 256 + threadIdx.x;
        if (t < 131072) {                    // Wt1 [256][512]
            int k = t & 511, nn = t >> 9;
            Wt1[t] = f2bf(W1[(size_t)k * 256 + nn]);
        } else if (t < 163840) {             // Wt2 [128][256]
            int u = t - 131072;
            int k = u & 255, nn = u >> 8;
            Wt2[u] = f2bf(W2[(size_t)k * 128 + nn]);
        } else {                             // Wt3 [64][128]
            int u = t - 163840;              // [0, 8192)
            int k = u & 127, nn = u >> 7;    // nn < 64
            Wt3[u] = f2bf(W3[(size_t)k * 64 + nn]);
        }
    } else {                                 // count_indeg (hides under conv_x)
        int t = (bx - nxblk - 672) * 256 + threadIdx.x;
        if (t < E) atomicAdd(&indeg[dst[t]], 1);
    }
}

// ---------------- CSR scan ----------------
__global__ __launch_bounds__(1024) void scan1(const int* __restrict__ indeg,
                                              int* __restrict__ incl,   // rowptr as temp
                                              int* __restrict__ part, int n) {
    __shared__ int sm[1024];
    int i = blockIdx.x * 1024 + threadIdx.x;
    int v = (i < n) ? indeg[i] : 0;
    sm[threadIdx.x] = v;
    __syncthreads();
    #pragma unroll
    for (int off = 1; off < 1024; off <<= 1) {
        int t = (threadIdx.x >= (unsigned)off) ? sm[threadIdx.x - off] : 0;
        __syncthreads();
        sm[threadIdx.x] += t;
        __syncthreads();
    }
    if (i < n) incl[i] = sm[threadIdx.x];
    if (threadIdx.x == 1023) part[blockIdx.x] = sm[1023];
}

__global__ __launch_bounds__(256) void scan23(const int* __restrict__ indeg,
                                              int* __restrict__ rowptr,
                                              int* __restrict__ cursor,
                                              const int* __restrict__ part,
                                              float* __restrict__ dinv,
                                              int n, int npad, int E, int nb) {
    __shared__ int ps[64];
    int tid = threadIdx.x;
    if (tid < 64) {
        int v = (tid < nb) ? part[tid] : 0;
        int orig = v;
        #pragma unroll
        for (int off = 1; off < 64; off <<= 1) {
            int u = __shfl_up(v, off, 64);
            if (tid >= off) v += u;
        }
        ps[tid] = v - orig;  // exclusive chunk offset
    }
    __syncthreads();
    int i = blockIdx.x * 256 + tid;
    if (i < n) {
        int excl = rowptr[i] - indeg[i] + ps[i >> 10];
        rowptr[i] = excl;
        cursor[i] = excl;
        dinv[i] = rsqrtf((float)indeg[i] + 1.0f);  // +1 self-loop
    } else if (i < npad) {
        dinv[i] = 0.f;                             // pad rows -> C rows are exact 0
    }
    if (i == 0) rowptr[n] = E;
}

// ---------------- k4: gemm1 (K=512, N=256) with EMBEDDED fill_csr ----------------
// Each of the 782 GEMM blocks also owns EPB (<=1024) edges: 4 atomic+scatter
// chains per thread, issued right after the prologue DMA so their latency
// hides under the MFMA K-loop. No LDS-starved tail blocks.
__global__ __launch_bounds__(256) void gemm1_fill(const ushort* __restrict__ A,
                                                  const ushort* __restrict__ Bt,
                                                  const float* __restrict__ dinv,
                                                  ushort* __restrict__ C,
                                                  const int* __restrict__ src,
                                                  const int* __restrict__ dst,
                                                  int* __restrict__ cursor,
                                                  int* __restrict__ colx,
                                                  int E, int EPB) {
    __shared__ __align__(16) ushort As[2 * 4096];
    __shared__ __align__(16) ushort Bs[2 * 4096];
    constexpr int K = 512;
    int bx = blockIdx.x;
    int tid = threadIdx.x;
    int lane = tid & 63, w = tid >> 6;
    int wr = w >> 1, wc = w & 1;
    int bm = (bx >> 1) * 128, bn = (bx & 1) * 128;

    float4_t acc[4][4];
    #pragma unroll
    for (int i = 0; i < 4; ++i)
        #pragma unroll
        for (int j = 0; j < 4; ++j) acc[i][j] = (float4_t)0.0f;

    int r0 = tid >> 2;
    int kb = (tid & 3) * 8;
    const ushort* ga0 = A + (size_t)(bm + r0) * K + kb;
    const ushort* ga1 = A + (size_t)(bm + r0 + 64) * K + kb;
    const ushort* gb0 = Bt + (size_t)(bn + r0) * K + kb;
    const ushort* gb1 = Bt + (size_t)(bn + r0 + 64) * K + kb;
    int w512 = w * 512;

#define ISSUE_DMA(kk, bufofs)                              \
    do {                                                   \
        GLDS16(ga0 + (kk), As + (bufofs) + w512);          \
        GLDS16(ga1 + (kk), As + (bufofs) + 2048 + w512);   \
        GLDS16(gb0 + (kk), Bs + (bufofs) + w512);          \
        GLDS16(gb1 + (kk), Bs + (bufofs) + 2048 + w512);   \
    } while (0)

    int arow = wr * 64 + (lane & 15);
    int brow = wc * 64 + (lane & 15);
    int quad = lane >> 4;

    ISSUE_DMA(0, 0);  // prologue -> buf0 (in flight during fill)

    // ---- embedded CSR fill: this block's edge slice (EPB <= 1024) ----
    {
        int ebase = bx * EPB + tid;
        #pragma unroll
        for (int u = 0; u < 4; ++u) {
            int e = ebase + u * 256;
            if ((u * 256 + tid) < EPB && e < E) {
                int p = atomicAdd(&cursor[dst[e]], 1);
                colx[p] = src[e];
            }
        }
    }

    for (int k0 = 0; k0 < K; k0 += 64) {
        __syncthreads();
        ISSUE_DMA(k0 + 32, 4096);
        {
            short8_t aF[4], bF[4];
            #pragma unroll
            for (int i = 0; i < 4; ++i)
                aF[i] = *(const short8_t*)&As[(arow + i * 16) * 32 + quad * 8];
            #pragma unroll
            for (int j = 0; j < 4; ++j)
                bF[j] = *(const short8_t*)&Bs[(brow + j * 16) * 32 + quad * 8];
            #pragma unroll
            for (int i = 0; i < 4; ++i)
                #pragma unroll
                for (int j = 0; j < 4; ++j)
                    acc[i][j] = __builtin_amdgcn_mfma_f32_16x16x32_bf16(aF[i], bF[j], acc[i][j], 0, 0, 0);
        }
        __syncthreads();
        if (k0 + 64 < K) ISSUE_DMA(k0 + 64, 0);
        {
            short8_t aF[4], bF[4];
            #pragma unroll
            for (int i = 0; i < 4; ++i)
                aF[i] = *(const short8_t*)&As[4096 + (arow + i * 16) * 32 + quad * 8];
            #pragma unroll
            for (int j = 0; j < 4; ++j)
                bF[j] = *(const short8_t*)&Bs[4096 + (brow + j * 16) * 32 + quad * 8];
            #pragma unroll
            for (int i = 0; i < 4; ++i)
                #pragma unroll
                for (int j = 0; j < 4; ++j)
                    acc[i][j] = __builtin_amdgcn_mfma_f32_16x16x32_bf16(aF[i], bF[j], acc[i][j], 0, 0, 0);
        }
    }
#undef ISSUE_DMA

    // C/D layout: col = lane&15, row = (lane>>4)*4 + reg
    int colb = bn + wc * 64 + (lane & 15);
    #pragma unroll
    for (int i = 0; i < 4; ++i) {
        int mb = bm + wr * 64 + i * 16 + quad * 4;
        #pragma unroll
        for (int r = 0; r < 4; ++r) {
            int m = mb + r;
            float s = dinv[m];
            #pragma unroll
            for (int j = 0; j < 4; ++j) {
                int n = colb + j * 16;
                C[(size_t)m * 256 + n] = f2bf(acc[i][j][r] * s);
            }
        }
    }
}

// ---------------- fused agg + gemm: block owns 128 rows ----------------
// Phase 1: 8 waves aggregate 16 rows each (bf16 gather from g, CSR), apply
//   dinv/bias/relu, write bf16 A-tile into LDS ([FIN/32][128][32] k-chunks).
// Phase 2: MFMA with B read directly from global (Wt L2-resident),
//   epilogue scales by dinv[m], writes bf16 C = next layer's gather source.
template <int FIN, int NOUT>
__global__ __launch_bounds__(512) void agg_gemm(const ushort* __restrict__ g,
                                                const int* __restrict__ rowptr,
                                                const int* __restrict__ col,
                                                const float* __restrict__ dinv,
                                                const float* __restrict__ bias,
                                                const ushort* __restrict__ Bt,  // [NOUT][FIN]
                                                ushort* __restrict__ C,         // [Mpad][NOUT]
                                                int n, int zrow) {
    constexpr int NCH = FIN / 32;        // k-chunks
    constexpr int EPT = FIN / 32;        // features per lane (32 lanes per row)
    constexpr int DWN = EPT / 2;         // dwords per gather load
    using vec_t = typename VecT<DWN>::type;
    __shared__ __align__(16) ushort As[NCH * 128 * 32];   // 64KB (FIN=256) / 32KB (FIN=128)

    int tid = threadIdx.x;
    int lane = tid & 63, wv = tid >> 6;  // 8 waves
    int bm = blockIdx.x * 128;
    int h = lane >> 5, sub = lane & 31;  // 2 edge slots x 32 lanes/row
    int off = sub * EPT;
    const ushort* gofs = g + off;
    int cch0 = off >> 5, kk0 = off & 31;

    // ---- phase 1: aggregate ----
    for (int q = 0; q < 16; ++q) {
        int r = wv * 16 + q;
        int m = bm + r;
        ushort* ap = As + cch0 * 4096 + r * 32 + kk0;
        if (m >= n) {                    // pad row -> exact zeros (avoid NaN in MFMA)
            if (h == 0) {
                #pragma unroll
                for (int d = 0; d < DWN; ++d) ((uint*)ap)[d] = 0;
            }
            continue;
        }
        vec_t sv = *(const vec_t*)(gofs + (size_t)m * FIN);
        float self[EPT], acc[EPT];
        #pragma unroll
        for (int d = 0; d < DWN; ++d) {
            uint dw = ((const uint*)&sv)[d];
            self[2 * d]     = __uint_as_float(dw << 16);
            self[2 * d + 1] = __uint_as_float(dw & 0xffff0000u);
        }
        #pragma unroll
        for (int t = 0; t < EPT; ++t) acc[t] = 0.f;

        int e0 = rowptr[m];
        int deg = rowptr[m + 1] - e0;
        for (int base = 0; base < deg; base += 64) {
            int cnt = min(64, deg - base);
            int ec = (lane < cnt) ? col[e0 + base + lane] : zrow;  // pad lanes -> zero row
            for (int j = 0; j < cnt; j += 16) {
                vec_t v[8];
                #pragma unroll
                for (int u = 0; u < 8; ++u) {
                    int id = __shfl(ec, j + u * 2 + h);
                    v[u] = *(const vec_t*)(gofs + (size_t)id * FIN);
                }
                #pragma unroll
                for (int u = 0; u < 8; ++u)
                    #pragma unroll
                    for (int d = 0; d < DWN; ++d) {
                        uint dw = ((const uint*)&v[u])[d];
                        acc[2 * d]     += __uint_as_float(dw << 16);
                        acc[2 * d + 1] += __uint_as_float(dw & 0xffff0000u);
                    }
            }
        }
        #pragma unroll
        for (int t = 0; t < EPT; ++t) acc[t] += __shfl_xor(acc[t], 32, 64);

        if (h == 0) {
            float di = dinv[m];
            uint pk[DWN];
            #pragma unroll
            for (int d = 0; d < DWN; ++d) {
                float r0 = fmaxf(di * (acc[2 * d]     + self[2 * d])     + bias[off + 2 * d],     0.f);
                float r1 = fmaxf(di * (acc[2 * d + 1] + self[2 * d + 1]) + bias[off + 2 * d + 1], 0.f);
                pk[d] = (uint)f2bf(r0) | ((uint)f2bf(r1) << 16);
            }
            #pragma unroll
            for (int d = 0; d < DWN; ++d) ((uint*)ap)[d] = pk[d];
        }
    }
    __syncthreads();

    // ---- phase 2: C[128 x NOUT] = dinv .* (A @ Bt^T) ----
    constexpr int WC = NOUT / 32;        // waves across N
    constexpr int WR = 8 / WC;           // waves across M
    constexpr int MI = 8 / WR;           // 16-row frags per wave
    int wr = wv / WC, wc = wv % WC;
    int quad = lane >> 4, l15 = lane & 15;
    float4_t acc2[MI][2];
    #pragma unroll
    for (int i = 0; i < MI; ++i) {
        acc2[i][0] = (float4_t)0.f;
        acc2[i][1] = (float4_t)0.f;
    }
    int arowb = wr * (MI * 16) + l15;
    const ushort* bp = Bt + (size_t)(wc * 32 + l15) * FIN + quad * 8;
    #pragma unroll
    for (int c = 0; c < NCH; ++c) {
        short8_t aF[MI], bF[2];
        #pragma unroll
        for (int i = 0; i < MI; ++i)
            aF[i] = *(const short8_t*)&As[c * 4096 + (arowb + i * 16) * 32 + quad * 8];
        #pragma unroll
        for (int j = 0; j < 2; ++j)
            bF[j] = *(const short8_t*)(bp + (size_t)(j * 16) * FIN + c * 32);
        #pragma unroll
        for (int i = 0; i < MI; ++i) {
            acc2[i][0] = __builtin_amdgcn_mfma_f32_16x16x32_bf16(aF[i], bF[0], acc2[i][0], 0, 0, 0);
            acc2[i][1] = __builtin_amdgcn_mfma_f32_16x16x32_bf16(aF[i], bF[1], acc2[i][1], 0, 0, 0);
        }
    }
    #pragma unroll
    for (int i = 0; i < MI; ++i) {
        int mb = bm + wr * (MI * 16) + i * 16 + quad * 4;
        #pragma unroll
        for (int rr = 0; rr < 4; ++rr) {
            int m = mb + rr;
            float s = dinv[m];
            #pragma unroll
            for (int j = 0; j < 2; ++j) {
                int ncol = wc * 32 + j * 16 + l15;
                C[(size_t)m * NOUT + ncol] = f2bf(acc2[i][j][rr] * s);
            }
        }
    }
}

// ---------------- standalone agg (layer 3, F=64, bf16) ----------------
template <int F, bool RELU>
__global__ __launch_bounds__(256) void agg_bf(const ushort* __restrict__ g,
                                              const int* __restrict__ rowptr,
                                              const int* __restrict__ col,
                                              const float* __restrict__ dinv,
                                              const float* __restrict__ bias,
                                              ushort* __restrict__ out,
                                              int n, int npad, int zrow) {
    constexpr int EPL  = (F == 64) ? 4 : 2;  // edges per load instruction
    constexpr int SUBW = 64 / EPL;           // lanes per edge
    constexpr int EPT  = F / SUBW;           // elements per lane
    constexpr int LPG  = 16 / EPL;           // loads per 16-edge flight group
    constexpr int DWN  = EPT / 2;            // dwords per load
    using vec_t = typename VecT<DWN>::type;

    int wid = (int)((blockIdx.x * blockDim.x + threadIdx.x) >> 6);
    int lane = threadIdx.x & 63;
    if (wid >= npad) return;
    int h   = lane / SUBW;
    int sub = lane & (SUBW - 1);
    int off = sub * EPT;
    ushort* orow = out + (size_t)wid * F + off;

    if (wid >= n) {  // zero padded tail rows
        if (h == 0) {
            #pragma unroll
            for (int d = 0; d < DWN; ++d) ((uint*)orow)[d] = 0;
        }
        return;
    }

    const ushort* gofs = g + off;
    vec_t sv = *(const vec_t*)(gofs + (size_t)wid * F);
    float self[EPT];
    #pragma unroll
    for (int d = 0; d < DWN; ++d) {
        uint dw = ((const uint*)&sv)[d];
        self[2 * d]     = __uint_as_float(dw << 16);
        self[2 * d + 1] = __uint_as_float(dw & 0xffff0000u);
    }

    float acc[EPT];
    #pragma unroll
    for (int t = 0; t < EPT; ++t) acc[t] = 0.f;

    int e0 = rowptr[wid];
    int deg = rowptr[wid + 1] - e0;

    for (int base = 0; base < deg; base += 64) {
        int cnt = min(64, deg - base);
        int ec = (lane < cnt) ? col[e0 + base + lane] : zrow;
        for (int j = 0; j < cnt; j += 16) {
            vec_t v[LPG];
            #pragma unroll
            for (int u = 0; u < LPG; ++u) {
                int id = __shfl(ec, j + u * EPL + h);
                v[u] = *(const vec_t*)(gofs + (size_t)id * F);
            }
            #pragma unroll
            for (int u = 0; u < LPG; ++u)
                #pragma unroll
                for (int d = 0; d < DWN; ++d) {
                    uint dw = ((const uint*)&v[u])[d];
                    acc[2 * d]     += __uint_as_float(dw << 16);
                    acc[2 * d + 1] += __uint_as_float(dw & 0xffff0000u);
                }
        }
    }

    #pragma unroll
    for (int t = 0; t < EPT; ++t) {
        if constexpr (EPL == 4) acc[t] += __shfl_xor(acc[t], 16, 64);
        acc[t] += __shfl_xor(acc[t], 32, 64);
    }

    float di = dinv[wid];
    ushort res[EPT];
    #pragma unroll
    for (int t = 0; t < EPT; ++t) {
        float r = di * (acc[t] + self[t]) + bias[off + t];
        if (RELU) r = fmaxf(r, 0.f);
        res[t] = f2bf(r);
    }
    if (h == 0) {
        #pragma unroll
        for (int d = 0; d < DWN; ++d)
            ((uint*)orow)[d] = (uint)res[2 * d] | ((uint)res[2 * d + 1] << 16);
    }
}

// ---------------- pooling + final linear ----------------

__global__ __launch_bounds__(256) void pool_sorted(const ushort* __restrict__ h,
                                                   const int* __restrict__ batch,
                                                   float* __restrict__ sums,
                                                   float* __restrict__ cnt, int n) {
    int wave = (int)((blockIdx.x * blockDim.x + threadIdx.x) >> 6);
    int lane = threadIdx.x & 63;
    int start = wave * 64;
    if (start >= n) return;
    int end = min(start + 64, n);
    float acc = 0.f;
    int cur = batch[start];
    int runlen = 0;
    for (int i = start; i < end; ++i) {
        int b = batch[i];
        if (b != cur) {
            atomicAdd(&sums[cur * 64 + lane], acc);
            if (lane == 0) atomicAdd(&cnt[cur], (float)runlen);
            acc = 0.f;
            runlen = 0;
            cur = b;
        }
        acc += bf2f(h[(size_t)i * 64 + lane]);
        runlen++;
    }
    atomicAdd(&sums[cur * 64 + lane], acc);
    if (lane == 0) atomicAdd(&cnt[cur], (float)runlen);
}

__global__ void final_lin(const float* __restrict__ sums, const float* __restrict__ cnt,
                          const float* __restrict__ Wl, const float* __restrict__ bl,
                          float* __restrict__ out) {
    int t = threadIdx.x;  // 128 threads: (graph, j)
    int g = t >> 1, j = t & 1;
    float c = fmaxf(cnt[g], 1.0f);
    float a = 0.f;
    #pragma unroll
    for (int k = 0; k < 64; ++k) a += sums[g * 64 + k] * Wl[k * 2 + j];
    out[t] = a / c + bl[j];
}

// ---------------- launch ----------------

extern "C" void kernel_launch(void* const* d_in, const int* in_sizes, int n_in,
                              void* d_out, int out_size, void* d_ws, size_t ws_size,
                              hipStream_t stream) {
    const float* x   = (const float*)d_in[0];
    const int*   ei  = (const int*)d_in[1];
    const int*   bat = (const int*)d_in[2];
    const float* W1  = (const float*)d_in[3];
    const float* b1  = (const float*)d_in[4];
    const float* W2  = (const float*)d_in[5];
    const float* b2  = (const float*)d_in[6];
    const float* W3  = (const float*)d_in[7];
    const float* b3  = (const float*)d_in[8];
    const float* Wl  = (const float*)d_in[9];
    const float* bl  = (const float*)d_in[10];
    float* out = (float*)d_out;

    const int N = in_sizes[0] / 512;
    const int E = in_sizes[1] / 2;
    const int Mpad = ((N + 127) / 128) * 128;   // 50048
    const int* src = ei;
    const int* dst = ei + E;

    char* w = (char*)d_ws;
    auto alloc = [&](size_t bytes) {
        char* p = w;
        w += (bytes + 255) & ~(size_t)255;
        return p;
    };
    ushort* Xb   = (ushort*)alloc((size_t)Mpad * 512 * 2);  // bf16 x
    ushort* G1   = (ushort*)alloc((size_t)Mpad * 256 * 2);  // gemm1 out / agg1 gather src
    ushort* G2   = (ushort*)alloc((size_t)Mpad * 128 * 2);  // k5 out / agg2 gather src
    ushort* G3   = (ushort*)alloc((size_t)Mpad * 64 * 2);   // k6 out / agg3 gather src
    ushort* H3   = (ushort*)alloc((size_t)Mpad * 64 * 2);   // agg3 out (pool input)
    ushort* Wt1  = (ushort*)alloc(256 * 512 * 2);
    ushort* Wt2  = (ushort*)alloc(128 * 256 * 2);
    ushort* Wt3  = (ushort*)alloc(64 * 128 * 2);
    float* dinv  = (float*)alloc((size_t)Mpad * 4);
    int* rowptr  = (int*)alloc((size_t)(N + 1) * 4);
    int* cursor  = (int*)alloc((size_t)N * 4);
    int* col     = (int*)alloc((size_t)(E + 16) * 4);
    int* part    = (int*)alloc(256 * 4);
    int nzero = N + 64 * 64 + 64;               // indeg + sums + cnt
    int* indeg   = (int*)alloc((size_t)nzero * 4);
    float* sums  = (float*)(indeg + N);
    float* cnt   = sums + 64 * 64;

    // k0: zero indeg + sums + cnt
    zero_k<<<(nzero + 255) / 256, 256, 0, stream>>>(indeg, nzero);

    // k1: conv_x + weight converts + count_indeg
    int nxblk = (Mpad * 128 + 255) / 256;       // conv_x blocks (t = float4 index)
    int ncblk = (E + 255) / 256;                // 3125
    prep<<<nxblk + 672 + ncblk, 256, 0, stream>>>(x, Xb, W1, Wt1, W2, Wt2, W3, Wt3,
                                                  dst, indeg, N, Mpad, E, nxblk);

    // CSR scan
    int nb = (N + 1023) / 1024;
    scan1<<<nb, 1024, 0, stream>>>(indeg, rowptr, part, N);
    scan23<<<(Mpad + 255) / 256, 256, 0, stream>>>(indeg, rowptr, cursor, part, dinv,
                                                   N, Mpad, E, nb);

    // k4: gemm1 (512->256) with embedded fill_csr
    int ngemm = (Mpad / 128) * 2;               // 782
    int EPB = (E + ngemm - 1) / ngemm;          // 1024 (<= 4*256 by construction)
    gemm1_fill<<<ngemm, 256, 0, stream>>>(Xb, Wt1, dinv, G1, src, dst,
                                          cursor, col, E, EPB);

    // k5: agg1 (relu, b1) + gemm2 (256->128) fused
    agg_gemm<256, 128><<<Mpad / 128, 512, 0, stream>>>(G1, rowptr, col, dinv, b1,
                                                       Wt2, G2, N, N);
    // k6: agg2 (relu, b2) + gemm3 (128->64) fused
    agg_gemm<128, 64><<<Mpad / 128, 512, 0, stream>>>(G2, rowptr, col, dinv, b2,
                                                      Wt3, G3, N, N);
    // agg3 (b3, no relu)
    agg_bf<64, false><<<Mpad / 4, 256, 0, stream>>>(G3, rowptr, col, dinv, b3, H3,
                                                    N, Mpad, N);

    pool_sorted<<<(N + 255) / 256, 256, 0, stream>>>(H3, bat, sums, cnt, N);
    final_lin<<<1, 128, 0, stream>>>(sums, cnt, Wl, bl, out);
}

// Round 4
// 446.199 us; speedup vs baseline: 1.0352x; 1.0352x over previous
//
#include <hip/hip_runtime.h>

// GCN: 3x gcn_conv + mean-pool + linear, bf16 MFMA pipeline, fused layers.
// out[i] = dinv[i] * (sum_{e: dst=i} g[src_e] + g[i]) + b,  g = dinv .* (x @ W)
// Structure: k0 zero -> k1 prep(conv_x+weights+count) -> scan1 -> scan23
//   -> fill_csr (standalone; fusing it into gemm1 measured WORSE: 85-100us vs ~70us split)
//   -> gemm1 -> k5 agg1+gemm2 (fused, LDS A-tile) -> k6 agg2+gemm3 -> agg3 -> pool -> final.

typedef __attribute__((ext_vector_type(8))) short short8_t;
typedef __attribute__((ext_vector_type(4))) float float4_t;

__device__ __forceinline__ unsigned short f2bf(float f) {
    unsigned int u = __float_as_uint(f);
    u += 0x7FFFu + ((u >> 16) & 1u);   // round-to-nearest-even
    return (unsigned short)(u >> 16);
}
__device__ __forceinline__ float bf2f(unsigned short h) {
    return __uint_as_float(((unsigned int)h) << 16);
}

// async global->LDS, 16B per lane; LDS dest is wave-uniform base + lane*16
#define GLDS16(gp, lp)                                                          \
    __builtin_amdgcn_global_load_lds(                                           \
        (const __attribute__((address_space(1))) void*)(gp),                    \
        (__attribute__((address_space(3))) void*)(lp), 16, 0, 0)

template <int DWN> struct VecT;
template <> struct VecT<2> { using type = uint2; };
template <> struct VecT<4> { using type = uint4; };

// ---------------- k0: zero indeg + sums + cnt ----------------
__global__ void zero_k(int* __restrict__ p, int n) {
    int i = blockIdx.x * blockDim.x + threadIdx.x;
    if (i < n) p[i] = 0;
}

// ---------------- k1: conv_x + weight transpose + count_indeg ----------------
__global__ __launch_bounds__(256) void prep(const float* __restrict__ x,
                                            ushort* __restrict__ Xb,
                                            const float* __restrict__ W1, ushort* __restrict__ Wt1,
                                            const float* __restrict__ W2, ushort* __restrict__ Wt2,
                                            const float* __restrict__ W3, ushort* __restrict__ Wt3,
                                            const int* __restrict__ dst, int* __restrict__ indeg,
                                            int M, int Mpad, int E, int nxblk) {
    int bx = blockIdx.x;
    if (bx < nxblk) {                        // conv_x: fp32 x -> bf16 Xb (padded)
        int t = bx * 256 + threadIdx.x;      // one float4 -> ushort4
        int row = t >> 7;
        ushort4 o;
        if (row < M) {
            float4 v = ((const float4*)x)[t];
            o.x = f2bf(v.x); o.y = f2bf(v.y); o.z = f2bf(v.z); o.w = f2bf(v.w);
        } else {
            o.x = o.y = o.z = o.w = 0;
        }
        if (row < Mpad) ((ushort4*)Xb)[t] = o;
    } else if (bx < nxblk + 672) {           // weight transpose+convert (672*256 = 172032)
        int t = (bx - nxblk) * 256 + threadIdx.x;
        if (t < 131072) {                    // Wt1 [256][512]
            int k = t & 511, nn = t >> 9;
            Wt1[t] = f2bf(W1[(size_t)k * 256 + nn]);
        } else if (t < 163840) {             // Wt2 [128][256]
            int u = t - 131072;
            int k = u & 255, nn = u >> 8;
            Wt2[u] = f2bf(W2[(size_t)k * 128 + nn]);
        } else {                             // Wt3 [64][128]
            int u = t - 163840;              // [0, 8192)
            int k = u & 127, nn = u >> 7;    // nn < 64
            Wt3[u] = f2bf(W3[(size_t)k * 64 + nn]);
        }
    } else {                                 // count_indeg (hides under conv_x)
        int t = (bx - nxblk - 672) * 256 + threadIdx.x;
        if (t < E) atomicAdd(&indeg[dst[t]], 1);
    }
}

// ---------------- CSR scan ----------------
__global__ __launch_bounds__(1024) void scan1(const int* __restrict__ indeg,
                                              int* __restrict__ incl,   // rowptr as temp
                                              int* __restrict__ part, int n) {
    __shared__ int sm[1024];
    int i = blockIdx.x * 1024 + threadIdx.x;
    int v = (i < n) ? indeg[i] : 0;
    sm[threadIdx.x] = v;
    __syncthreads();
    #pragma unroll
    for (int off = 1; off < 1024; off <<= 1) {
        int t = (threadIdx.x >= (unsigned)off) ? sm[threadIdx.x - off] : 0;
        __syncthreads();
        sm[threadIdx.x] += t;
        __syncthreads();
    }
    if (i < n) incl[i] = sm[threadIdx.x];
    if (threadIdx.x == 1023) part[blockIdx.x] = sm[1023];
}

__global__ __launch_bounds__(256) void scan23(const int* __restrict__ indeg,
                                              int* __restrict__ rowptr,
                                              int* __restrict__ cursor,
                                              const int* __restrict__ part,
                                              float* __restrict__ dinv,
                                              int n, int npad, int E, int nb) {
    __shared__ int ps[64];
    int tid = threadIdx.x;
    if (tid < 64) {
        int v = (tid < nb) ? part[tid] : 0;
        int orig = v;
        #pragma unroll
        for (int off = 1; off < 64; off <<= 1) {
            int u = __shfl_up(v, off, 64);
            if (tid >= off) v += u;
        }
        ps[tid] = v - orig;  // exclusive chunk offset
    }
    __syncthreads();
    int i = blockIdx.x * 256 + tid;
    if (i < n) {
        int excl = rowptr[i] - indeg[i] + ps[i >> 10];
        rowptr[i] = excl;
        cursor[i] = excl;
        dinv[i] = rsqrtf((float)indeg[i] + 1.0f);  // +1 self-loop
    } else if (i < npad) {
        dinv[i] = 0.f;                             // pad rows -> C rows are exact 0
    }
    if (i == 0) rowptr[n] = E;
}

// ---------------- fill_csr: standalone (atomic cursor + scatter) ----------------
__global__ void fill_csr(const int* __restrict__ src, const int* __restrict__ dst,
                         int* __restrict__ cursor, int* __restrict__ col, int E) {
    int e = blockIdx.x * blockDim.x + threadIdx.x;
    if (e < E) {
        int p = atomicAdd(&cursor[dst[e]], 1);
        col[p] = src[e];
    }
}

// ---------------- gemm1 (K=512, N=256), 128x128 tile, double-buffered GLDS ----------------
__global__ __launch_bounds__(256) void gemm1(const ushort* __restrict__ A,
                                             const ushort* __restrict__ Bt,
                                             const float* __restrict__ dinv,
                                             ushort* __restrict__ C) {
    __shared__ __align__(16) ushort As[2 * 4096];
    __shared__ __align__(16) ushort Bs[2 * 4096];
    constexpr int K = 512;
    int bx = blockIdx.x;
    int tid = threadIdx.x;
    int lane = tid & 63, w = tid >> 6;
    int wr = w >> 1, wc = w & 1;
    int bm = (bx >> 1) * 128, bn = (bx & 1) * 128;

    float4_t acc[4][4];
    #pragma unroll
    for (int i = 0; i < 4; ++i)
        #pragma unroll
        for (int j = 0; j < 4; ++j) acc[i][j] = (float4_t)0.0f;

    int r0 = tid >> 2;
    int kb = (tid & 3) * 8;
    const ushort* ga0 = A + (size_t)(bm + r0) * K + kb;
    const ushort* ga1 = A + (size_t)(bm + r0 + 64) * K + kb;
    const ushort* gb0 = Bt + (size_t)(bn + r0) * K + kb;
    const ushort* gb1 = Bt + (size_t)(bn + r0 + 64) * K + kb;
    int w512 = w * 512;

#define ISSUE_DMA(kk, bufofs)                              \
    do {                                                   \
        GLDS16(ga0 + (kk), As + (bufofs) + w512);          \
        GLDS16(ga1 + (kk), As + (bufofs) + 2048 + w512);   \
        GLDS16(gb0 + (kk), Bs + (bufofs) + w512);          \
        GLDS16(gb1 + (kk), Bs + (bufofs) + 2048 + w512);   \
    } while (0)

    int arow = wr * 64 + (lane & 15);
    int brow = wc * 64 + (lane & 15);
    int quad = lane >> 4;

    ISSUE_DMA(0, 0);  // prologue -> buf0
    for (int k0 = 0; k0 < K; k0 += 64) {
        __syncthreads();
        ISSUE_DMA(k0 + 32, 4096);
        {
            short8_t aF[4], bF[4];
            #pragma unroll
            for (int i = 0; i < 4; ++i)
                aF[i] = *(const short8_t*)&As[(arow + i * 16) * 32 + quad * 8];
            #pragma unroll
            for (int j = 0; j < 4; ++j)
                bF[j] = *(const short8_t*)&Bs[(brow + j * 16) * 32 + quad * 8];
            #pragma unroll
            for (int i = 0; i < 4; ++i)
                #pragma unroll
                for (int j = 0; j < 4; ++j)
                    acc[i][j] = __builtin_amdgcn_mfma_f32_16x16x32_bf16(aF[i], bF[j], acc[i][j], 0, 0, 0);
        }
        __syncthreads();
        if (k0 + 64 < K) ISSUE_DMA(k0 + 64, 0);
        {
            short8_t aF[4], bF[4];
            #pragma unroll
            for (int i = 0; i < 4; ++i)
                aF[i] = *(const short8_t*)&As[4096 + (arow + i * 16) * 32 + quad * 8];
            #pragma unroll
            for (int j = 0; j < 4; ++j)
                bF[j] = *(const short8_t*)&Bs[4096 + (brow + j * 16) * 32 + quad * 8];
            #pragma unroll
            for (int i = 0; i < 4; ++i)
                #pragma unroll
                for (int j = 0; j < 4; ++j)
                    acc[i][j] = __builtin_amdgcn_mfma_f32_16x16x32_bf16(aF[i], bF[j], acc[i][j], 0, 0, 0);
        }
    }
#undef ISSUE_DMA

    // C/D layout: col = lane&15, row = (lane>>4)*4 + reg
    int colb = bn + wc * 64 + (lane & 15);
    #pragma unroll
    for (int i = 0; i < 4; ++i) {
        int mb = bm + wr * 64 + i * 16 + quad * 4;
        #pragma unroll
        for (int r = 0; r < 4; ++r) {
            int m = mb + r;
            float s = dinv[m];
            #pragma unroll
            for (int j = 0; j < 4; ++j) {
                int n = colb + j * 16;
                C[(size_t)m * 256 + n] = f2bf(acc[i][j][r] * s);
            }
        }
    }
}

// ---------------- fused agg + gemm: block owns 128 rows ----------------
// Phase 1: 8 waves aggregate 16 rows each (bf16 gather from g, CSR), apply
//   dinv/bias/relu, write bf16 A-tile into LDS ([FIN/32][128][32] k-chunks).
// Phase 2: MFMA with B read directly from global (Wt L2-resident),
//   epilogue scales by dinv[m], writes bf16 C = next layer's gather source.
template <int FIN, int NOUT>
__global__ __launch_bounds__(512) void agg_gemm(const ushort* __restrict__ g,
                                                const int* __restrict__ rowptr,
                                                const int* __restrict__ col,
                                                const float* __restrict__ dinv,
                                                const float* __restrict__ bias,
                                                const ushort* __restrict__ Bt,  // [NOUT][FIN]
                                                ushort* __restrict__ C,         // [Mpad][NOUT]
                                                int n, int zrow) {
    constexpr int NCH = FIN / 32;        // k-chunks
    constexpr int EPT = FIN / 32;        // features per lane (32 lanes per row)
    constexpr int DWN = EPT / 2;         // dwords per gather load
    using vec_t = typename VecT<DWN>::type;
    __shared__ __align__(16) ushort As[NCH * 128 * 32];   // 64KB (FIN=256) / 32KB (FIN=128)

    int tid = threadIdx.x;
    int lane = tid & 63, wv = tid >> 6;  // 8 waves
    int bm = blockIdx.x * 128;
    int h = lane >> 5, sub = lane & 31;  // 2 edge slots x 32 lanes/row
    int off = sub * EPT;
    const ushort* gofs = g + off;
    int cch0 = off >> 5, kk0 = off & 31;

    // ---- phase 1: aggregate ----
    for (int q = 0; q < 16; ++q) {
        int r = wv * 16 + q;
        int m = bm + r;
        ushort* ap = As + cch0 * 4096 + r * 32 + kk0;
        if (m >= n) {                    // pad row -> exact zeros (avoid NaN in MFMA)
            if (h == 0) {
                #pragma unroll
                for (int d = 0; d < DWN; ++d) ((uint*)ap)[d] = 0;
            }
            continue;
        }
        vec_t sv = *(const vec_t*)(gofs + (size_t)m * FIN);
        float self[EPT], acc[EPT];
        #pragma unroll
        for (int d = 0; d < DWN; ++d) {
            uint dw = ((const uint*)&sv)[d];
            self[2 * d]     = __uint_as_float(dw << 16);
            self[2 * d + 1] = __uint_as_float(dw & 0xffff0000u);
        }
        #pragma unroll
        for (int t = 0; t < EPT; ++t) acc[t] = 0.f;

        int e0 = rowptr[m];
        int deg = rowptr[m + 1] - e0;
        for (int base = 0; base < deg; base += 64) {
            int cnt = min(64, deg - base);
            int ec = (lane < cnt) ? col[e0 + base + lane] : zrow;  // pad lanes -> zero row
            for (int j = 0; j < cnt; j += 16) {
                vec_t v[8];
                #pragma unroll
                for (int u = 0; u < 8; ++u) {
                    int id = __shfl(ec, j + u * 2 + h);
                    v[u] = *(const vec_t*)(gofs + (size_t)id * FIN);
                }
                #pragma unroll
                for (int u = 0; u < 8; ++u)
                    #pragma unroll
                    for (int d = 0; d < DWN; ++d) {
                        uint dw = ((const uint*)&v[u])[d];
                        acc[2 * d]     += __uint_as_float(dw << 16);
                        acc[2 * d + 1] += __uint_as_float(dw & 0xffff0000u);
                    }
            }
        }
        #pragma unroll
        for (int t = 0; t < EPT; ++t) acc[t] += __shfl_xor(acc[t], 32, 64);

        if (h == 0) {
            float di = dinv[m];
            uint pk[DWN];
            #pragma unroll
            for (int d = 0; d < DWN; ++d) {
                float r0 = fmaxf(di * (acc[2 * d]     + self[2 * d])     + bias[off + 2 * d],     0.f);
                float r1 = fmaxf(di * (acc[2 * d + 1] + self[2 * d + 1]) + bias[off + 2 * d + 1], 0.f);
                pk[d] = (uint)f2bf(r0) | ((uint)f2bf(r1) << 16);
            }
            #pragma unroll
            for (int d = 0; d < DWN; ++d) ((uint*)ap)[d] = pk[d];
        }
    }
    __syncthreads();

    // ---- phase 2: C[128 x NOUT] = dinv .* (A @ Bt^T) ----
    constexpr int WC = NOUT / 32;        // waves across N
    constexpr int WR = 8 / WC;           // waves across M
    constexpr int MI = 8 / WR;           // 16-row frags per wave
    int wr = wv / WC, wc = wv % WC;
    int quad = lane >> 4, l15 = lane & 15;
    float4_t acc2[MI][2];
    #pragma unroll
    for (int i = 0; i < MI; ++i) {
        acc2[i][0] = (float4_t)0.f;
        acc2[i][1] = (float4_t)0.f;
    }
    int arowb = wr * (MI * 16) + l15;
    const ushort* bp = Bt + (size_t)(wc * 32 + l15) * FIN + quad * 8;
    #pragma unroll
    for (int c = 0; c < NCH; ++c) {
        short8_t aF[MI], bF[2];
        #pragma unroll
        for (int i = 0; i < MI; ++i)
            aF[i] = *(const short8_t*)&As[c * 4096 + (arowb + i * 16) * 32 + quad * 8];
        #pragma unroll
        for (int j = 0; j < 2; ++j)
            bF[j] = *(const short8_t*)(bp + (size_t)(j * 16) * FIN + c * 32);
        #pragma unroll
        for (int i = 0; i < MI; ++i) {
            acc2[i][0] = __builtin_amdgcn_mfma_f32_16x16x32_bf16(aF[i], bF[0], acc2[i][0], 0, 0, 0);
            acc2[i][1] = __builtin_amdgcn_mfma_f32_16x16x32_bf16(aF[i], bF[1], acc2[i][1], 0, 0, 0);
        }
    }
    #pragma unroll
    for (int i = 0; i < MI; ++i) {
        int mb = bm + wr * (MI * 16) + i * 16 + quad * 4;
        #pragma unroll
        for (int rr = 0; rr < 4; ++rr) {
            int m = mb + rr;
            float s = dinv[m];
            #pragma unroll
            for (int j = 0; j < 2; ++j) {
                int ncol = wc * 32 + j * 16 + l15;
                C[(size_t)m * NOUT + ncol] = f2bf(acc2[i][j][rr] * s);
            }
        }
    }
}

// ---------------- standalone agg (layer 3, F=64, bf16) ----------------
template <int F, bool RELU>
__global__ __launch_bounds__(256) void agg_bf(const ushort* __restrict__ g,
                                              const int* __restrict__ rowptr,
                                              const int* __restrict__ col,
                                              const float* __restrict__ dinv,
                                              const float* __restrict__ bias,
                                              ushort* __restrict__ out,
                                              int n, int npad, int zrow) {
    constexpr int EPL  = (F == 64) ? 4 : 2;  // edges per load instruction
    constexpr int SUBW = 64 / EPL;           // lanes per edge
    constexpr int EPT  = F / SUBW;           // elements per lane
    constexpr int LPG  = 16 / EPL;           // loads per 16-edge flight group
    constexpr int DWN  = EPT / 2;            // dwords per load
    using vec_t = typename VecT<DWN>::type;

    int wid = (int)((blockIdx.x * blockDim.x + threadIdx.x) >> 6);
    int lane = threadIdx.x & 63;
    if (wid >= npad) return;
    int h   = lane / SUBW;
    int sub = lane & (SUBW - 1);
    int off = sub * EPT;
    ushort* orow = out + (size_t)wid * F + off;

    if (wid >= n) {  // zero padded tail rows
        if (h == 0) {
            #pragma unroll
            for (int d = 0; d < DWN; ++d) ((uint*)orow)[d] = 0;
        }
        return;
    }

    const ushort* gofs = g + off;
    vec_t sv = *(const vec_t*)(gofs + (size_t)wid * F);
    float self[EPT];
    #pragma unroll
    for (int d = 0; d < DWN; ++d) {
        uint dw = ((const uint*)&sv)[d];
        self[2 * d]     = __uint_as_float(dw << 16);
        self[2 * d + 1] = __uint_as_float(dw & 0xffff0000u);
    }

    float acc[EPT];
    #pragma unroll
    for (int t = 0; t < EPT; ++t) acc[t] = 0.f;

    int e0 = rowptr[wid];
    int deg = rowptr[wid + 1] - e0;

    for (int base = 0; base < deg; base += 64) {
        int cnt = min(64, deg - base);
        int ec = (lane < cnt) ? col[e0 + base + lane] : zrow;
        for (int j = 0; j < cnt; j += 16) {
            vec_t v[LPG];
            #pragma unroll
            for (int u = 0; u < LPG; ++u) {
                int id = __shfl(ec, j + u * EPL + h);
                v[u] = *(const vec_t*)(gofs + (size_t)id * F);
            }
            #pragma unroll
            for (int u = 0; u < LPG; ++u)
                #pragma unroll
                for (int d = 0; d < DWN; ++d) {
                    uint dw = ((const uint*)&v[u])[d];
                    acc[2 * d]     += __uint_as_float(dw << 16);
                    acc[2 * d + 1] += __uint_as_float(dw & 0xffff0000u);
                }
        }
    }

    #pragma unroll
    for (int t = 0; t < EPT; ++t) {
        if constexpr (EPL == 4) acc[t] += __shfl_xor(acc[t], 16, 64);
        acc[t] += __shfl_xor(acc[t], 32, 64);
    }

    float di = dinv[wid];
    ushort res[EPT];
    #pragma unroll
    for (int t = 0; t < EPT; ++t) {
        float r = di * (acc[t] + self[t]) + bias[off + t];
        if (RELU) r = fmaxf(r, 0.f);
        res[t] = f2bf(r);
    }
    if (h == 0) {
        #pragma unroll
        for (int d = 0; d < DWN; ++d)
            ((uint*)orow)[d] = (uint)res[2 * d] | ((uint)res[2 * d + 1] << 16);
    }
}

// ---------------- pooling + final linear ----------------

__global__ __launch_bounds__(256) void pool_sorted(const ushort* __restrict__ h,
                                                   const int* __restrict__ batch,
                                                   float* __restrict__ sums,
                                                   float* __restrict__ cnt, int n) {
    int wave = (int)((blockIdx.x * blockDim.x + threadIdx.x) >> 6);
    int lane = threadIdx.x & 63;
    int start = wave * 64;
    if (start >= n) return;
    int end = min(start + 64, n);
    float acc = 0.f;
    int cur = batch[start];
    int runlen = 0;
    for (int i = start; i < end; ++i) {
        int b = batch[i];
        if (b != cur) {
            atomicAdd(&sums[cur * 64 + lane], acc);
            if (lane == 0) atomicAdd(&cnt[cur], (float)runlen);
            acc = 0.f;
            runlen = 0;
            cur = b;
        }
        acc += bf2f(h[(size_t)i * 64 + lane]);
        runlen++;
    }
    atomicAdd(&sums[cur * 64 + lane], acc);
    if (lane == 0) atomicAdd(&cnt[cur], (float)runlen);
}

__global__ void final_lin(const float* __restrict__ sums, const float* __restrict__ cnt,
                          const float* __restrict__ Wl, const float* __restrict__ bl,
                          float* __restrict__ out) {
    int t = threadIdx.x;  // 128 threads: (graph, j)
    int g = t >> 1, j = t & 1;
    float c = fmaxf(cnt[g], 1.0f);
    float a = 0.f;
    #pragma unroll
    for (int k = 0; k < 64; ++k) a += sums[g * 64 + k] * Wl[k * 2 + j];
    out[t] = a / c + bl[j];
}

// ---------------- launch ----------------

extern "C" void kernel_launch(void* const* d_in, const int* in_sizes, int n_in,
                              void* d_out, int out_size, void* d_ws, size_t ws_size,
                              hipStream_t stream) {
    const float* x   = (const float*)d_in[0];
    const int*   ei  = (const int*)d_in[1];
    const int*   bat = (const int*)d_in[2];
    const float* W1  = (const float*)d_in[3];
    const float* b1  = (const float*)d_in[4];
    const float* W2  = (const float*)d_in[5];
    const float* b2  = (const float*)d_in[6];
    const float* W3  = (const float*)d_in[7];
    const float* b3  = (const float*)d_in[8];
    const float* Wl  = (const float*)d_in[9];
    const float* bl  = (const float*)d_in[10];
    float* out = (float*)d_out;

    const int N = in_sizes[0] / 512;
    const int E = in_sizes[1] / 2;
    const int Mpad = ((N + 127) / 128) * 128;   // 50048
    const int* src = ei;
    const int* dst = ei + E;

    char* w = (char*)d_ws;
    auto alloc = [&](size_t bytes) {
        char* p = w;
        w += (bytes + 255) & ~(size_t)255;
        return p;
    };
    ushort* Xb   = (ushort*)alloc((size_t)Mpad * 512 * 2);  // bf16 x
    ushort* G1   = (ushort*)alloc((size_t)Mpad * 256 * 2);  // gemm1 out / agg1 gather src
    ushort* G2   = (ushort*)alloc((size_t)Mpad * 128 * 2);  // k5 out / agg2 gather src
    ushort* G3   = (ushort*)alloc((size_t)Mpad * 64 * 2);   // k6 out / agg3 gather src
    ushort* H3   = (ushort*)alloc((size_t)Mpad * 64 * 2);   // agg3 out (pool input)
    ushort* Wt1  = (ushort*)alloc(256 * 512 * 2);
    ushort* Wt2  = (ushort*)alloc(128 * 256 * 2);
    ushort* Wt3  = (ushort*)alloc(64 * 128 * 2);
    float* dinv  = (float*)alloc((size_t)Mpad * 4);
    int* rowptr  = (int*)alloc((size_t)(N + 1) * 4);
    int* cursor  = (int*)alloc((size_t)N * 4);
    int* col     = (int*)alloc((size_t)(E + 16) * 4);
    int* part    = (int*)alloc(256 * 4);
    int nzero = N + 64 * 64 + 64;               // indeg + sums + cnt
    int* indeg   = (int*)alloc((size_t)nzero * 4);
    float* sums  = (float*)(indeg + N);
    float* cnt   = sums + 64 * 64;

    // k0: zero indeg + sums + cnt
    zero_k<<<(nzero + 255) / 256, 256, 0, stream>>>(indeg, nzero);

    // k1: conv_x + weight converts + count_indeg
    int nxblk = (Mpad * 128 + 255) / 256;       // conv_x blocks (t = float4 index)
    int ncblk = (E + 255) / 256;                // 3125
    prep<<<nxblk + 672 + ncblk, 256, 0, stream>>>(x, Xb, W1, Wt1, W2, Wt2, W3, Wt3,
                                                  dst, indeg, N, Mpad, E, nxblk);

    // CSR scan
    int nb = (N + 1023) / 1024;
    scan1<<<nb, 1024, 0, stream>>>(indeg, rowptr, part, N);
    scan23<<<(Mpad + 255) / 256, 256, 0, stream>>>(indeg, rowptr, cursor, part, dinv,
                                                   N, Mpad, E, nb);

    // fill_csr (standalone — fused variants measured slower)
    fill_csr<<<ncblk, 256, 0, stream>>>(src, dst, cursor, col, E);

    // gemm1 (512->256)
    gemm1<<<(Mpad / 128) * 2, 256, 0, stream>>>(Xb, Wt1, dinv, G1);

    // k5: agg1 (relu, b1) + gemm2 (256->128) fused
    agg_gemm<256, 128><<<Mpad / 128, 512, 0, stream>>>(G1, rowptr, col, dinv, b1,
                                                       Wt2, G2, N, N);
    // k6: agg2 (relu, b2) + gemm3 (128->64) fused
    agg_gemm<128, 64><<<Mpad / 128, 512, 0, stream>>>(G2, rowptr, col, dinv, b2,
                                                      Wt3, G3, N, N);
    // agg3 (b3, no relu)
    agg_bf<64, false><<<Mpad / 4, 256, 0, stream>>>(G3, rowptr, col, dinv, b3, H3,
                                                    N, Mpad, N);

    pool_sorted<<<(N + 255) / 256, 256, 0, stream>>>(H3, bat, sums, cnt, N);
    final_lin<<<1, 128, 0, stream>>>(sums, cnt, Wl, bl, out);
}

// Round 6
// 444.606 us; speedup vs baseline: 1.0389x; 1.0036x over previous
//
#include <hip/hip_runtime.h>

// GCN: 3x gcn_conv + mean-pool + linear, bf16 MFMA pipeline, fused layers.
// out[i] = dinv[i] * (sum_{e: dst=i} g[src_e] + g[i]) + b,  g = dinv .* (x @ W)
// Structure: k0 zero -> k1 prep(conv_x+weights+count8) -> scan1 -> scan23
//   -> fill_csr (8-sliced cursors) -> gemm1 -> k5 agg1+gemm2 (fused, LDS A-tile)
//   -> k6 agg2+gemm3 -> agg3 -> pool -> final.
// Atomic histograms are 8-way sliced by edge-block (blockIdx&7 ~ XCD under
// round-robin dispatch): kills same-line serialization + cross-XCD ping-pong
// (R4: prep 74us @ 22% HBM, 4% VALU = atomic-contention-bound).

typedef __attribute__((ext_vector_type(8))) short short8_t;
typedef __attribute__((ext_vector_type(4))) float float4_t;

__device__ __forceinline__ unsigned short f2bf(float f) {
    unsigned int u = __float_as_uint(f);
    u += 0x7FFFu + ((u >> 16) & 1u);   // round-to-nearest-even
    return (unsigned short)(u >> 16);
}
__device__ __forceinline__ float bf2f(unsigned short h) {
    return __uint_as_float(((unsigned int)h) << 16);
}

// async global->LDS, 16B per lane; LDS dest is wave-uniform base + lane*16
#define GLDS16(gp, lp)                                                          \
    __builtin_amdgcn_global_load_lds(                                           \
        (const __attribute__((address_space(1))) void*)(gp),                    \
        (__attribute__((address_space(3))) void*)(lp), 16, 0, 0)

template <int DWN> struct VecT;
template <> struct VecT<2> { using type = uint2; };
template <> struct VecT<4> { using type = uint4; };

// ---------------- k0: zero indeg8 + sums + cnt ----------------
__global__ void zero_k(int* __restrict__ p, int n) {
    int i = blockIdx.x * blockDim.x + threadIdx.x;
    if (i < n) p[i] = 0;
}

// ---------------- k1: conv_x + weight transpose + count_indeg (8-sliced) ----------------
__global__ __launch_bounds__(256) void prep(const float* __restrict__ x,
                                            ushort* __restrict__ Xb,
                                            const float* __restrict__ W1, ushort* __restrict__ Wt1,
                                            const float* __restrict__ W2, ushort* __restrict__ Wt2,
                                            const float* __restrict__ W3, ushort* __restrict__ Wt3,
                                            const int* __restrict__ dst, int* __restrict__ indeg8,
                                            int M, int Mpad, int E, int nxblk) {
    int bx = blockIdx.x;
    if (bx < nxblk) {                        // conv_x: fp32 x -> bf16 Xb (padded)
        int t = bx * 256 + threadIdx.x;      // one float4 -> ushort4
        int row = t >> 7;
        ushort4 o;
        if (row < M) {
            float4 v = ((const float4*)x)[t];
            o.x = f2bf(v.x); o.y = f2bf(v.y); o.z = f2bf(v.z); o.w = f2bf(v.w);
        } else {
            o.x = o.y = o.z = o.w = 0;
        }
        if (row < Mpad) ((ushort4*)Xb)[t] = o;
    } else if (bx < nxblk + 672) {           // weight transpose+convert (672*256 = 172032)
        int t = (bx - nxblk) * 256 + threadIdx.x;
        if (t < 131072) {                    // Wt1 [256][512]
            int k = t & 511, nn = t >> 9;
            Wt1[t] = f2bf(W1[(size_t)k * 256 + nn]);
        } else if (t < 163840) {             // Wt2 [128][256]
            int u = t - 131072;
            int k = u & 255, nn = u >> 8;
            Wt2[u] = f2bf(W2[(size_t)k * 128 + nn]);
        } else {                             // Wt3 [64][128]
            int u = t - 163840;              // [0, 8192)
            int k = u & 127, nn = u >> 7;    // nn < 64
            Wt3[u] = f2bf(W3[(size_t)k * 64 + nn]);
        }
    } else {                                 // count_indeg, 8-way sliced by edge-block
        int cb = bx - nxblk - 672;           // edge-block index (matches fill_csr's)
        int t = cb * 256 + threadIdx.x;
        if (t < E) atomicAdd(&indeg8[(size_t)(cb & 7) * Mpad + dst[t]], 1);
    }
}

// ---------------- CSR scan ----------------
__global__ __launch_bounds__(1024) void scan1(const int* __restrict__ indeg8,
                                              int* __restrict__ incl,   // rowptr as temp
                                              int* __restrict__ part, int n, int Mpad) {
    __shared__ int sm[1024];
    int i = blockIdx.x * 1024 + threadIdx.x;
    int v = 0;
    if (i < n) {
        #pragma unroll
        for (int c = 0; c < 8; ++c) v += indeg8[(size_t)c * Mpad + i];
    }
    sm[threadIdx.x] = v;
    __syncthreads();
    #pragma unroll
    for (int off = 1; off < 1024; off <<= 1) {
        int t = (threadIdx.x >= (unsigned)off) ? sm[threadIdx.x - off] : 0;
        __syncthreads();
        sm[threadIdx.x] += t;
        __syncthreads();
    }
    if (i < n) incl[i] = sm[threadIdx.x];
    if (threadIdx.x == 1023) part[blockIdx.x] = sm[1023];
}

__global__ __launch_bounds__(256) void scan23(const int* __restrict__ indeg8,
                                              int* __restrict__ rowptr,
                                              int* __restrict__ cursor8,
                                              const int* __restrict__ part,
                                              float* __restrict__ dinv,
                                              int n, int npad, int E, int nb) {
    __shared__ int ps[64];
    int tid = threadIdx.x;
    if (tid < 64) {
        int v = (tid < nb) ? part[tid] : 0;
        int orig = v;
        #pragma unroll
        for (int off = 1; off < 64; off <<= 1) {
            int u = __shfl_up(v, off, 64);
            if (tid >= off) v += u;
        }
        ps[tid] = v - orig;  // exclusive chunk offset
    }
    __syncthreads();
    int i = blockIdx.x * 256 + tid;
    if (i < n) {
        int d8[8], deg = 0;
        #pragma unroll
        for (int c = 0; c < 8; ++c) {
            d8[c] = indeg8[(size_t)c * npad + i];
            deg += d8[c];
        }
        int excl = rowptr[i] - deg + ps[i >> 10];
        rowptr[i] = excl;
        int run = excl;
        #pragma unroll
        for (int c = 0; c < 8; ++c) {        // per-copy exclusive cursors
            cursor8[(size_t)c * npad + i] = run;
            run += d8[c];
        }
        dinv[i] = rsqrtf((float)deg + 1.0f); // +1 self-loop
    } else if (i < npad) {
        dinv[i] = 0.f;                       // pad rows -> C rows are exact 0
    }
    if (i == 0) rowptr[n] = E;
}

// ---------------- fill_csr: 8-sliced cursors (same edge-block mapping as count) ----------------
__global__ void fill_csr(const int* __restrict__ src, const int* __restrict__ dst,
                         int* __restrict__ cursor8, int* __restrict__ col,
                         int E, int Mpad) {
    int bx = blockIdx.x;
    int e = bx * 256 + threadIdx.x;
    if (e < E) {
        int p = atomicAdd(&cursor8[(size_t)(bx & 7) * Mpad + dst[e]], 1);
        col[p] = src[e];
    }
}

// ---------------- gemm1 (K=512, N=256), 128x128 tile, double-buffered GLDS ----------------
__global__ __launch_bounds__(256) void gemm1(const ushort* __restrict__ A,
                                             const ushort* __restrict__ Bt,
                                             const float* __restrict__ dinv,
                                             ushort* __restrict__ C) {
    __shared__ __align__(16) ushort As[2 * 4096];
    __shared__ __align__(16) ushort Bs[2 * 4096];
    constexpr int K = 512;
    int bx = blockIdx.x;
    int tid = threadIdx.x;
    int lane = tid & 63, w = tid >> 6;
    int wr = w >> 1, wc = w & 1;
    int bm = (bx >> 1) * 128, bn = (bx & 1) * 128;

    float4_t acc[4][4];
    #pragma unroll
    for (int i = 0; i < 4; ++i)
        #pragma unroll
        for (int j = 0; j < 4; ++j) acc[i][j] = (float4_t)0.0f;

    int r0 = tid >> 2;
    int kb = (tid & 3) * 8;
    const ushort* ga0 = A + (size_t)(bm + r0) * K + kb;
    const ushort* ga1 = A + (size_t)(bm + r0 + 64) * K + kb;
    const ushort* gb0 = Bt + (size_t)(bn + r0) * K + kb;
    const ushort* gb1 = Bt + (size_t)(bn + r0 + 64) * K + kb;
    int w512 = w * 512;

#define ISSUE_DMA(kk, bufofs)                              \
    do {                                                   \
        GLDS16(ga0 + (kk), As + (bufofs) + w512);          \
        GLDS16(ga1 + (kk), As + (bufofs) + 2048 + w512);   \
        GLDS16(gb0 + (kk), Bs + (bufofs) + w512);          \
        GLDS16(gb1 + (kk), Bs + (bufofs) + 2048 + w512);   \
    } while (0)

    int arow = wr * 64 + (lane & 15);
    int brow = wc * 64 + (lane & 15);
    int quad = lane >> 4;

    ISSUE_DMA(0, 0);  // prologue -> buf0
    for (int k0 = 0; k0 < K; k0 += 64) {
        __syncthreads();
        ISSUE_DMA(k0 + 32, 4096);
        {
            short8_t aF[4], bF[4];
            #pragma unroll
            for (int i = 0; i < 4; ++i)
                aF[i] = *(const short8_t*)&As[(arow + i * 16) * 32 + quad * 8];
            #pragma unroll
            for (int j = 0; j < 4; ++j)
                bF[j] = *(const short8_t*)&Bs[(brow + j * 16) * 32 + quad * 8];
            #pragma unroll
            for (int i = 0; i < 4; ++i)
                #pragma unroll
                for (int j = 0; j < 4; ++j)
                    acc[i][j] = __builtin_amdgcn_mfma_f32_16x16x32_bf16(aF[i], bF[j], acc[i][j], 0, 0, 0);
        }
        __syncthreads();
        if (k0 + 64 < K) ISSUE_DMA(k0 + 64, 0);
        {
            short8_t aF[4], bF[4];
            #pragma unroll
            for (int i = 0; i < 4; ++i)
                aF[i] = *(const short8_t*)&As[4096 + (arow + i * 16) * 32 + quad * 8];
            #pragma unroll
            for (int j = 0; j < 4; ++j)
                bF[j] = *(const short8_t*)&Bs[4096 + (brow + j * 16) * 32 + quad * 8];
            #pragma unroll
            for (int i = 0; i < 4; ++i)
                #pragma unroll
                for (int j = 0; j < 4; ++j)
                    acc[i][j] = __builtin_amdgcn_mfma_f32_16x16x32_bf16(aF[i], bF[j], acc[i][j], 0, 0, 0);
        }
    }
#undef ISSUE_DMA

    // C/D layout: col = lane&15, row = (lane>>4)*4 + reg
    int colb = bn + wc * 64 + (lane & 15);
    #pragma unroll
    for (int i = 0; i < 4; ++i) {
        int mb = bm + wr * 64 + i * 16 + quad * 4;
        #pragma unroll
        for (int r = 0; r < 4; ++r) {
            int m = mb + r;
            float s = dinv[m];
            #pragma unroll
            for (int j = 0; j < 4; ++j) {
                int n = colb + j * 16;
                C[(size_t)m * 256 + n] = f2bf(acc[i][j][r] * s);
            }
        }
    }
}

// ---------------- fused agg + gemm: block owns 128 rows ----------------
// Phase 1: 8 waves aggregate 16 rows each (bf16 gather from g, CSR), apply
//   dinv/bias/relu, write bf16 A-tile into LDS ([FIN/32][128][32] k-chunks).
// Phase 2: MFMA with B read directly from global (Wt L2-resident),
//   epilogue scales by dinv[m], writes bf16 C = next layer's gather source.
template <int FIN, int NOUT>
__global__ __launch_bounds__(512) void agg_gemm(const ushort* __restrict__ g,
                                                const int* __restrict__ rowptr,
                                                const int* __restrict__ col,
                                                const float* __restrict__ dinv,
                                                const float* __restrict__ bias,
                                                const ushort* __restrict__ Bt,  // [NOUT][FIN]
                                                ushort* __restrict__ C,         // [Mpad][NOUT]
                                                int n, int zrow) {
    constexpr int NCH = FIN / 32;        // k-chunks
    constexpr int EPT = FIN / 32;        // features per lane (32 lanes per row)
    constexpr int DWN = EPT / 2;         // dwords per gather load
    using vec_t = typename VecT<DWN>::type;
    __shared__ __align__(16) ushort As[NCH * 128 * 32];   // 64KB (FIN=256) / 32KB (FIN=128)

    int tid = threadIdx.x;
    int lane = tid & 63, wv = tid >> 6;  // 8 waves
    int bm = blockIdx.x * 128;
    int h = lane >> 5, sub = lane & 31;  // 2 edge slots x 32 lanes/row
    int off = sub * EPT;
    const ushort* gofs = g + off;
    int cch0 = off >> 5, kk0 = off & 31;

    // ---- phase 1: aggregate ----
    for (int q = 0; q < 16; ++q) {
        int r = wv * 16 + q;
        int m = bm + r;
        ushort* ap = As + cch0 * 4096 + r * 32 + kk0;
        if (m >= n) {                    // pad row -> exact zeros (avoid NaN in MFMA)
            if (h == 0) {
                #pragma unroll
                for (int d = 0; d < DWN; ++d) ((uint*)ap)[d] = 0;
            }
            continue;
        }
        vec_t sv = *(const vec_t*)(gofs + (size_t)m * FIN);
        float self[EPT], acc[EPT];
        #pragma unroll
        for (int d = 0; d < DWN; ++d) {
            uint dw = ((const uint*)&sv)[d];
            self[2 * d]     = __uint_as_float(dw << 16);
            self[2 * d + 1] = __uint_as_float(dw & 0xffff0000u);
        }
        #pragma unroll
        for (int t = 0; t < EPT; ++t) acc[t] = 0.f;

        int e0 = rowptr[m];
        int deg = rowptr[m + 1] - e0;
        for (int base = 0; base < deg; base += 64) {
            int cnt = min(64, deg - base);
            int ec = (lane < cnt) ? col[e0 + base + lane] : zrow;  // pad lanes -> zero row
            for (int j = 0; j < cnt; j += 16) {
                vec_t v[8];
                #pragma unroll
                for (int u = 0; u < 8; ++u) {
                    int id = __shfl(ec, j + u * 2 + h);
                    v[u] = *(const vec_t*)(gofs + (size_t)id * FIN);
                }
                #pragma unroll
                for (int u = 0; u < 8; ++u)
                    #pragma unroll
                    for (int d = 0; d < DWN; ++d) {
                        uint dw = ((const uint*)&v[u])[d];
                        acc[2 * d]     += __uint_as_float(dw << 16);
                        acc[2 * d + 1] += __uint_as_float(dw & 0xffff0000u);
                    }
            }
        }
        #pragma unroll
        for (int t = 0; t < EPT; ++t) acc[t] += __shfl_xor(acc[t], 32, 64);

        if (h == 0) {
            float di = dinv[m];
            uint pk[DWN];
            #pragma unroll
            for (int d = 0; d < DWN; ++d) {
                float r0 = fmaxf(di * (acc[2 * d]     + self[2 * d])     + bias[off + 2 * d],     0.f);
                float r1 = fmaxf(di * (acc[2 * d + 1] + self[2 * d + 1]) + bias[off + 2 * d + 1], 0.f);
                pk[d] = (uint)f2bf(r0) | ((uint)f2bf(r1) << 16);
            }
            #pragma unroll
            for (int d = 0; d < DWN; ++d) ((uint*)ap)[d] = pk[d];
        }
    }
    __syncthreads();

    // ---- phase 2: C[128 x NOUT] = dinv .* (A @ Bt^T) ----
    constexpr int WC = NOUT / 32;        // waves across N
    constexpr int WR = 8 / WC;           // waves across M
    constexpr int MI = 8 / WR;           // 16-row frags per wave
    int wr = wv / WC, wc = wv % WC;
    int quad = lane >> 4, l15 = lane & 15;
    float4_t acc2[MI][2];
    #pragma unroll
    for (int i = 0; i < MI; ++i) {
        acc2[i][0] = (float4_t)0.f;
        acc2[i][1] = (float4_t)0.f;
    }
    int arowb = wr * (MI * 16) + l15;
    const ushort* bp = Bt + (size_t)(wc * 32 + l15) * FIN + quad * 8;
    #pragma unroll
    for (int c = 0; c < NCH; ++c) {
        short8_t aF[MI], bF[2];
        #pragma unroll
        for (int i = 0; i < MI; ++i)
            aF[i] = *(const short8_t*)&As[c * 4096 + (arowb + i * 16) * 32 + quad * 8];
        #pragma unroll
        for (int j = 0; j < 2; ++j)
            bF[j] = *(const short8_t*)(bp + (size_t)(j * 16) * FIN + c * 32);
        #pragma unroll
        for (int i = 0; i < MI; ++i) {
            acc2[i][0] = __builtin_amdgcn_mfma_f32_16x16x32_bf16(aF[i], bF[0], acc2[i][0], 0, 0, 0);
            acc2[i][1] = __builtin_amdgcn_mfma_f32_16x16x32_bf16(aF[i], bF[1], acc2[i][1], 0, 0, 0);
        }
    }
    #pragma unroll
    for (int i = 0; i < MI; ++i) {
        int mb = bm + wr * (MI * 16) + i * 16 + quad * 4;
        #pragma unroll
        for (int rr = 0; rr < 4; ++rr) {
            int m = mb + rr;
            float s = dinv[m];
            #pragma unroll
            for (int j = 0; j < 2; ++j) {
                int ncol = wc * 32 + j * 16 + l15;
                C[(size_t)m * NOUT + ncol] = f2bf(acc2[i][j][rr] * s);
            }
        }
    }
}

// ---------------- standalone agg (layer 3, F=64, bf16) ----------------
template <int F, bool RELU>
__global__ __launch_bounds__(256) void agg_bf(const ushort* __restrict__ g,
                                              const int* __restrict__ rowptr,
                                              const int* __restrict__ col,
                                              const float* __restrict__ dinv,
                                              const float* __restrict__ bias,
                                              ushort* __restrict__ out,
                                              int n, int npad, int zrow) {
    constexpr int EPL  = (F == 64) ? 4 : 2;  // edges per load instruction
    constexpr int SUBW = 64 / EPL;           // lanes per edge
    constexpr int EPT  = F / SUBW;           // elements per lane
    constexpr int LPG  = 16 / EPL;           // loads per 16-edge flight group
    constexpr int DWN  = EPT / 2;            // dwords per load
    using vec_t = typename VecT<DWN>::type;

    int wid = (int)((blockIdx.x * blockDim.x + threadIdx.x) >> 6);
    int lane = threadIdx.x & 63;
    if (wid >= npad) return;
    int h   = lane / SUBW;
    int sub = lane & (SUBW - 1);
    int off = sub * EPT;
    ushort* orow = out + (size_t)wid * F + off;

    if (wid >= n) {  // zero padded tail rows
        if (h == 0) {
            #pragma unroll
            for (int d = 0; d < DWN; ++d) ((uint*)orow)[d] = 0;
        }
        return;
    }

    const ushort* gofs = g + off;
    vec_t sv = *(const vec_t*)(gofs + (size_t)wid * F);
    float self[EPT];
    #pragma unroll
    for (int d = 0; d < DWN; ++d) {
        uint dw = ((const uint*)&sv)[d];
        self[2 * d]     = __uint_as_float(dw << 16);
        self[2 * d + 1] = __uint_as_float(dw & 0xffff0000u);
    }

    float acc[EPT];
    #pragma unroll
    for (int t = 0; t < EPT; ++t) acc[t] = 0.f;

    int e0 = rowptr[wid];
    int deg = rowptr[wid + 1] - e0;

    for (int base = 0; base < deg; base += 64) {
        int cnt = min(64, deg - base);
        int ec = (lane < cnt) ? col[e0 + base + lane] : zrow;
        for (int j = 0; j < cnt; j += 16) {
            vec_t v[LPG];
            #pragma unroll
            for (int u = 0; u < LPG; ++u) {
                int id = __shfl(ec, j + u * EPL + h);
                v[u] = *(const vec_t*)(gofs + (size_t)id * F);
            }
            #pragma unroll
            for (int u = 0; u < LPG; ++u)
                #pragma unroll
                for (int d = 0; d < DWN; ++d) {
                    uint dw = ((const uint*)&v[u])[d];
                    acc[2 * d]     += __uint_as_float(dw << 16);
                    acc[2 * d + 1] += __uint_as_float(dw & 0xffff0000u);
                }
        }
    }

    #pragma unroll
    for (int t = 0; t < EPT; ++t) {
        if constexpr (EPL == 4) acc[t] += __shfl_xor(acc[t], 16, 64);
        acc[t] += __shfl_xor(acc[t], 32, 64);
    }

    float di = dinv[wid];
    ushort res[EPT];
    #pragma unroll
    for (int t = 0; t < EPT; ++t) {
        float r = di * (acc[t] + self[t]) + bias[off + t];
        if (RELU) r = fmaxf(r, 0.f);
        res[t] = f2bf(r);
    }
    if (h == 0) {
        #pragma unroll
        for (int d = 0; d < DWN; ++d)
            ((uint*)orow)[d] = (uint)res[2 * d] | ((uint)res[2 * d + 1] << 16);
    }
}

// ---------------- pooling + final linear ----------------

__global__ __launch_bounds__(256) void pool_sorted(const ushort* __restrict__ h,
                                                   const int* __restrict__ batch,
                                                   float* __restrict__ sums,
                                                   float* __restrict__ cnt, int n) {
    int wave = (int)((blockIdx.x * blockDim.x + threadIdx.x) >> 6);
    int lane = threadIdx.x & 63;
    int start = wave * 64;
    if (start >= n) return;
    int end = min(start + 64, n);
    float acc = 0.f;
    int cur = batch[start];
    int runlen = 0;
    for (int i = start; i < end; ++i) {
        int b = batch[i];
        if (b != cur) {
            atomicAdd(&sums[cur * 64 + lane], acc);
            if (lane == 0) atomicAdd(&cnt[cur], (float)runlen);
            acc = 0.f;
            runlen = 0;
            cur = b;
        }
        acc += bf2f(h[(size_t)i * 64 + lane]);
        runlen++;
    }
    atomicAdd(&sums[cur * 64 + lane], acc);
    if (lane == 0) atomicAdd(&cnt[cur], (float)runlen);
}

__global__ void final_lin(const float* __restrict__ sums, const float* __restrict__ cnt,
                          const float* __restrict__ Wl, const float* __restrict__ bl,
                          float* __restrict__ out) {
    int t = threadIdx.x;  // 128 threads: (graph, j)
    int g = t >> 1, j = t & 1;
    float c = fmaxf(cnt[g], 1.0f);
    float a = 0.f;
    #pragma unroll
    for (int k = 0; k < 64; ++k) a += sums[g * 64 + k] * Wl[k * 2 + j];
    out[t] = a / c + bl[j];
}

// ---------------- launch ----------------

extern "C" void kernel_launch(void* const* d_in, const int* in_sizes, int n_in,
                              void* d_out, int out_size, void* d_ws, size_t ws_size,
                              hipStream_t stream) {
    const float* x   = (const float*)d_in[0];
    const int*   ei  = (const int*)d_in[1];
    const int*   bat = (const int*)d_in[2];
    const float* W1  = (const float*)d_in[3];
    const float* b1  = (const float*)d_in[4];
    const float* W2  = (const float*)d_in[5];
    const float* b2  = (const float*)d_in[6];
    const float* W3  = (const float*)d_in[7];
    const float* b3  = (const float*)d_in[8];
    const float* Wl  = (const float*)d_in[9];
    const float* bl  = (const float*)d_in[10];
    float* out = (float*)d_out;

    const int N = in_sizes[0] / 512;
    const int E = in_sizes[1] / 2;
    const int Mpad = ((N + 127) / 128) * 128;   // 50048
    const int* src = ei;
    const int* dst = ei + E;

    char* w = (char*)d_ws;
    auto alloc = [&](size_t bytes) {
        char* p = w;
        w += (bytes + 255) & ~(size_t)255;
        return p;
    };
    ushort* Xb   = (ushort*)alloc((size_t)Mpad * 512 * 2);  // bf16 x
    ushort* G1   = (ushort*)alloc((size_t)Mpad * 256 * 2);  // gemm1 out / agg1 gather src
    ushort* G2   = (ushort*)alloc((size_t)Mpad * 128 * 2);  // k5 out / agg2 gather src
    ushort* G3   = (ushort*)alloc((size_t)Mpad * 64 * 2);   // k6 out / agg3 gather src
    ushort* H3   = (ushort*)alloc((size_t)Mpad * 64 * 2);   // agg3 out (pool input)
    ushort* Wt1  = (ushort*)alloc(256 * 512 * 2);
    ushort* Wt2  = (ushort*)alloc(128 * 256 * 2);
    ushort* Wt3  = (ushort*)alloc(64 * 128 * 2);
    float* dinv  = (float*)alloc((size_t)Mpad * 4);
    int* rowptr  = (int*)alloc((size_t)(N + 1) * 4);
    int* cursor8 = (int*)alloc((size_t)8 * Mpad * 4);
    int* col     = (int*)alloc((size_t)(E + 16) * 4);
    int* part    = (int*)alloc(256 * 4);
    int nzero = 8 * Mpad + 64 * 64 + 64;        // indeg8 + sums + cnt
    int* indeg8  = (int*)alloc((size_t)nzero * 4);
    float* sums  = (float*)(indeg8 + 8 * Mpad);
    float* cnt   = sums + 64 * 64;

    // k0: zero indeg8 + sums + cnt
    zero_k<<<(nzero + 255) / 256, 256, 0, stream>>>(indeg8, nzero);

    // k1: conv_x + weight converts + count_indeg (8-sliced)
    int nxblk = (Mpad * 128 + 255) / 256;       // conv_x blocks (t = float4 index)
    int ncblk = (E + 255) / 256;                // 3125
    prep<<<nxblk + 672 + ncblk, 256, 0, stream>>>(x, Xb, W1, Wt1, W2, Wt2, W3, Wt3,
                                                  dst, indeg8, N, Mpad, E, nxblk);

    // CSR scan
    int nb = (N + 1023) / 1024;
    scan1<<<nb, 1024, 0, stream>>>(indeg8, rowptr, part, N, Mpad);
    scan23<<<(Mpad + 255) / 256, 256, 0, stream>>>(indeg8, rowptr, cursor8, part, dinv,
                                                   N, Mpad, E, nb);

    // fill_csr (8-sliced cursors; same edge-block->copy mapping as count)
    fill_csr<<<ncblk, 256, 0, stream>>>(src, dst, cursor8, col, E, Mpad);

    // gemm1 (512->256)
    gemm1<<<(Mpad / 128) * 2, 256, 0, stream>>>(Xb, Wt1, dinv, G1);

    // k5: agg1 (relu, b1) + gemm2 (256->128) fused
    agg_gemm<256, 128><<<Mpad / 128, 512, 0, stream>>>(G1, rowptr, col, dinv, b1,
                                                       Wt2, G2, N, N);
    // k6: agg2 (relu, b2) + gemm3 (128->64) fused
    agg_gemm<128, 64><<<Mpad / 128, 512, 0, stream>>>(G2, rowptr, col, dinv, b2,
                                                      Wt3, G3, N, N);
    // agg3 (b3, no relu)
    agg_bf<64, false><<<Mpad / 4, 256, 0, stream>>>(G3, rowptr, col, dinv, b3, H3,
                                                    N, Mpad, N);

    pool_sorted<<<(N + 255) / 256, 256, 0, stream>>>(H3, bat, sums, cnt, N);
    final_lin<<<1, 128, 0, stream>>>(sums, cnt, Wl, bl, out);
}

// Round 8
// 423.113 us; speedup vs baseline: 1.0917x; 1.0508x over previous
//
#include <hip/hip_runtime.h>

// GCN: 3x gcn_conv + mean-pool + linear, bf16 MFMA pipeline, fused layers.
// out[i] = dinv[i] * (sum_{e: dst=i} g[src_e] + g[i]) + b,  g = dinv .* (x @ W)
// Structure: k0 zero -> k1 prep(conv_x ∥ weights ∥ count, INTERLEAVED) -> scan1
//   -> scan23 -> fill_csr -> gemm1 -> k5 agg1+gemm2 (BM=64 tiles) -> k6 agg2+gemm3
//   -> agg3 -> pool -> final.
// R6 lessons: atomic 8-slicing = null (fabric-resolved); prep's sections were
// serializing in dispatch order -> interleave count blocks every 9th block.
// agg_gemm was occupancy-starved (391 blocks, 27%) -> BM=64, 782 blocks, 4/CU.

typedef __attribute__((ext_vector_type(8))) short short8_t;
typedef __attribute__((ext_vector_type(4))) float float4_t;

__device__ __forceinline__ unsigned short f2bf(float f) {
    unsigned int u = __float_as_uint(f);
    u += 0x7FFFu + ((u >> 16) & 1u);   // round-to-nearest-even
    return (unsigned short)(u >> 16);
}
__device__ __forceinline__ float bf2f(unsigned short h) {
    return __uint_as_float(((unsigned int)h) << 16);
}

// async global->LDS, 16B per lane; LDS dest is wave-uniform base + lane*16
#define GLDS16(gp, lp)                                                          \
    __builtin_amdgcn_global_load_lds(                                           \
        (const __attribute__((address_space(1))) void*)(gp),                    \
        (__attribute__((address_space(3))) void*)(lp), 16, 0, 0)

template <int DWN> struct VecT;
template <> struct VecT<2> { using type = uint2; };
template <> struct VecT<4> { using type = uint4; };

// ---------------- k0: zero indeg8 + sums + cnt ----------------
__global__ void zero_k(int* __restrict__ p, int n) {
    int i = blockIdx.x * blockDim.x + threadIdx.x;
    if (i < n) p[i] = 0;
}

// ---------------- k1: conv_x ∥ weights ∥ count_indeg, interleaved ----------------
// Every 9th block (bx%9==8) is a count block -> atomic-fabric latency overlaps
// the conv_x bandwidth stream instead of running as a serialized tail.
__global__ __launch_bounds__(256) void prep(const float* __restrict__ x,
                                            ushort* __restrict__ Xb,
                                            const float* __restrict__ W1, ushort* __restrict__ Wt1,
                                            const float* __restrict__ W2, ushort* __restrict__ Wt2,
                                            const float* __restrict__ W3, ushort* __restrict__ Wt3,
                                            const int* __restrict__ dst, int* __restrict__ indeg8,
                                            int M, int Mpad, int E, int nxblk, int ncblk) {
    int bx = blockIdx.x;
    if ((bx % 9) == 8) {                     // count_indeg, 8-way sliced by edge-block
        int cb = bx / 9;                     // edge-block index (matches fill_csr's)
        if (cb < ncblk) {
            int t = cb * 256 + threadIdx.x;
            if (t < E) atomicAdd(&indeg8[(size_t)(cb & 7) * Mpad + dst[t]], 1);
        }
        return;
    }
    int ox = bx - (bx + 1) / 9;              // non-count index
    if (ox < nxblk) {                        // conv_x: fp32 x -> bf16 Xb (padded)
        int t = ox * 256 + threadIdx.x;      // one float4 -> ushort4
        int row = t >> 7;
        ushort4 o;
        if (row < M) {
            float4 v = ((const float4*)x)[t];
            o.x = f2bf(v.x); o.y = f2bf(v.y); o.z = f2bf(v.z); o.w = f2bf(v.w);
        } else {
            o.x = o.y = o.z = o.w = 0;
        }
        if (row < Mpad) ((ushort4*)Xb)[t] = o;
    } else {                                 // weight transpose+convert (172032 elems)
        int t = (ox - nxblk) * 256 + threadIdx.x;
        if (t < 131072) {                    // Wt1 [256][512]
            int k = t & 511, nn = t >> 9;
            Wt1[t] = f2bf(W1[(size_t)k * 256 + nn]);
        } else if (t < 163840) {             // Wt2 [128][256]
            int u = t - 131072;
            int k = u & 255, nn = u >> 8;
            Wt2[u] = f2bf(W2[(size_t)k * 128 + nn]);
        } else if (t < 172032) {             // Wt3 [64][128]
            int u = t - 163840;              // [0, 8192)
            int k = u & 127, nn = u >> 7;    // nn < 64
            Wt3[u] = f2bf(W3[(size_t)k * 64 + nn]);
        }
    }
}

// ---------------- CSR scan ----------------
__global__ __launch_bounds__(1024) void scan1(const int* __restrict__ indeg8,
                                              int* __restrict__ incl,   // rowptr as temp
                                              int* __restrict__ part, int n, int Mpad) {
    __shared__ int sm[1024];
    int i = blockIdx.x * 1024 + threadIdx.x;
    int v = 0;
    if (i < n) {
        #pragma unroll
        for (int c = 0; c < 8; ++c) v += indeg8[(size_t)c * Mpad + i];
    }
    sm[threadIdx.x] = v;
    __syncthreads();
    #pragma unroll
    for (int off = 1; off < 1024; off <<= 1) {
        int t = (threadIdx.x >= (unsigned)off) ? sm[threadIdx.x - off] : 0;
        __syncthreads();
        sm[threadIdx.x] += t;
        __syncthreads();
    }
    if (i < n) incl[i] = sm[threadIdx.x];
    if (threadIdx.x == 1023) part[blockIdx.x] = sm[1023];
}

__global__ __launch_bounds__(256) void scan23(const int* __restrict__ indeg8,
                                              int* __restrict__ rowptr,
                                              int* __restrict__ cursor8,
                                              const int* __restrict__ part,
                                              float* __restrict__ dinv,
                                              int n, int npad, int E, int nb) {
    __shared__ int ps[64];
    int tid = threadIdx.x;
    if (tid < 64) {
        int v = (tid < nb) ? part[tid] : 0;
        int orig = v;
        #pragma unroll
        for (int off = 1; off < 64; off <<= 1) {
            int u = __shfl_up(v, off, 64);
            if (tid >= off) v += u;
        }
        ps[tid] = v - orig;  // exclusive chunk offset
    }
    __syncthreads();
    int i = blockIdx.x * 256 + tid;
    if (i < n) {
        int d8[8], deg = 0;
        #pragma unroll
        for (int c = 0; c < 8; ++c) {
            d8[c] = indeg8[(size_t)c * npad + i];
            deg += d8[c];
        }
        int excl = rowptr[i] - deg + ps[i >> 10];
        rowptr[i] = excl;
        int run = excl;
        #pragma unroll
        for (int c = 0; c < 8; ++c) {        // per-copy exclusive cursors
            cursor8[(size_t)c * npad + i] = run;
            run += d8[c];
        }
        dinv[i] = rsqrtf((float)deg + 1.0f); // +1 self-loop
    } else if (i < npad) {
        dinv[i] = 0.f;                       // pad rows -> C rows are exact 0
    }
    if (i == 0) rowptr[n] = E;
}

// ---------------- fill_csr: 8-sliced cursors (same edge-block mapping as count) ----------------
__global__ void fill_csr(const int* __restrict__ src, const int* __restrict__ dst,
                         int* __restrict__ cursor8, int* __restrict__ col,
                         int E, int Mpad) {
    int bx = blockIdx.x;
    int e = bx * 256 + threadIdx.x;
    if (e < E) {
        int p = atomicAdd(&cursor8[(size_t)(bx & 7) * Mpad + dst[e]], 1);
        col[p] = src[e];
    }
}

// ---------------- gemm1 (K=512, N=256), 128x128 tile, double-buffered GLDS ----------------
__global__ __launch_bounds__(256) void gemm1(const ushort* __restrict__ A,
                                             const ushort* __restrict__ Bt,
                                             const float* __restrict__ dinv,
                                             ushort* __restrict__ C) {
    __shared__ __align__(16) ushort As[2 * 4096];
    __shared__ __align__(16) ushort Bs[2 * 4096];
    constexpr int K = 512;
    int bx = blockIdx.x;
    int tid = threadIdx.x;
    int lane = tid & 63, w = tid >> 6;
    int wr = w >> 1, wc = w & 1;
    int bm = (bx >> 1) * 128, bn = (bx & 1) * 128;

    float4_t acc[4][4];
    #pragma unroll
    for (int i = 0; i < 4; ++i)
        #pragma unroll
        for (int j = 0; j < 4; ++j) acc[i][j] = (float4_t)0.0f;

    int r0 = tid >> 2;
    int kb = (tid & 3) * 8;
    const ushort* ga0 = A + (size_t)(bm + r0) * K + kb;
    const ushort* ga1 = A + (size_t)(bm + r0 + 64) * K + kb;
    const ushort* gb0 = Bt + (size_t)(bn + r0) * K + kb;
    const ushort* gb1 = Bt + (size_t)(bn + r0 + 64) * K + kb;
    int w512 = w * 512;

#define ISSUE_DMA(kk, bufofs)                              \
    do {                                                   \
        GLDS16(ga0 + (kk), As + (bufofs) + w512);          \
        GLDS16(ga1 + (kk), As + (bufofs) + 2048 + w512);   \
        GLDS16(gb0 + (kk), Bs + (bufofs) + w512);          \
        GLDS16(gb1 + (kk), Bs + (bufofs) + 2048 + w512);   \
    } while (0)

    int arow = wr * 64 + (lane & 15);
    int brow = wc * 64 + (lane & 15);
    int quad = lane >> 4;

    ISSUE_DMA(0, 0);  // prologue -> buf0
    for (int k0 = 0; k0 < K; k0 += 64) {
        __syncthreads();
        ISSUE_DMA(k0 + 32, 4096);
        {
            short8_t aF[4], bF[4];
            #pragma unroll
            for (int i = 0; i < 4; ++i)
                aF[i] = *(const short8_t*)&As[(arow + i * 16) * 32 + quad * 8];
            #pragma unroll
            for (int j = 0; j < 4; ++j)
                bF[j] = *(const short8_t*)&Bs[(brow + j * 16) * 32 + quad * 8];
            #pragma unroll
            for (int i = 0; i < 4; ++i)
                #pragma unroll
                for (int j = 0; j < 4; ++j)
                    acc[i][j] = __builtin_amdgcn_mfma_f32_16x16x32_bf16(aF[i], bF[j], acc[i][j], 0, 0, 0);
        }
        __syncthreads();
        if (k0 + 64 < K) ISSUE_DMA(k0 + 64, 0);
        {
            short8_t aF[4], bF[4];
            #pragma unroll
            for (int i = 0; i < 4; ++i)
                aF[i] = *(const short8_t*)&As[4096 + (arow + i * 16) * 32 + quad * 8];
            #pragma unroll
            for (int j = 0; j < 4; ++j)
                bF[j] = *(const short8_t*)&Bs[4096 + (brow + j * 16) * 32 + quad * 8];
            #pragma unroll
            for (int i = 0; i < 4; ++i)
                #pragma unroll
                for (int j = 0; j < 4; ++j)
                    acc[i][j] = __builtin_amdgcn_mfma_f32_16x16x32_bf16(aF[i], bF[j], acc[i][j], 0, 0, 0);
        }
    }
#undef ISSUE_DMA

    // C/D layout: col = lane&15, row = (lane>>4)*4 + reg
    int colb = bn + wc * 64 + (lane & 15);
    #pragma unroll
    for (int i = 0; i < 4; ++i) {
        int mb = bm + wr * 64 + i * 16 + quad * 4;
        #pragma unroll
        for (int r = 0; r < 4; ++r) {
            int m = mb + r;
            float s = dinv[m];
            #pragma unroll
            for (int j = 0; j < 4; ++j) {
                int n = colb + j * 16;
                C[(size_t)m * 256 + n] = f2bf(acc[i][j][r] * s);
            }
        }
    }
}

// ---------------- fused agg + gemm: block owns 64 rows (occupancy-first) ----------------
// Phase 1: 8 waves aggregate 8 rows each (bf16 gather from g, CSR), apply
//   dinv/bias/relu, write bf16 A-tile into LDS ([FIN/32][64][32] k-chunks).
// Phase 2: 64xNOUT MFMA with B read from global (Wt L2-resident), epilogue
//   scales by dinv[m], writes bf16 C = next layer's gather source.
// BM=64: 782 blocks, 32/16 KB LDS -> 4 blocks/CU, ~32 waves/CU (vs 27% at BM=128).
template <int FIN, int NOUT>
__global__ __launch_bounds__(512) void agg_gemm(const ushort* __restrict__ g,
                                                const int* __restrict__ rowptr,
                                                const int* __restrict__ col,
                                                const float* __restrict__ dinv,
                                                const float* __restrict__ bias,
                                                const ushort* __restrict__ Bt,  // [NOUT][FIN]
                                                ushort* __restrict__ C,         // [Mpad][NOUT]
                                                int n, int zrow) {
    constexpr int NCH = FIN / 32;        // k-chunks
    constexpr int EPT = FIN / 32;        // features per lane (32 lanes per row)
    constexpr int DWN = EPT / 2;         // dwords per gather load
    using vec_t = typename VecT<DWN>::type;
    __shared__ __align__(16) ushort As[NCH * 64 * 32];    // 32KB (FIN=256) / 16KB (FIN=128)

    int tid = threadIdx.x;
    int lane = tid & 63, wv = tid >> 6;  // 8 waves
    int bm = blockIdx.x * 64;
    int h = lane >> 5, sub = lane & 31;  // 2 edge slots x 32 lanes/row
    int off = sub * EPT;
    const ushort* gofs = g + off;
    int cch0 = off >> 5, kk0 = off & 31;

    // ---- phase 1: aggregate (8 rows per wave) ----
    for (int q = 0; q < 8; ++q) {
        int r = wv * 8 + q;
        int m = bm + r;
        ushort* ap = As + cch0 * 2048 + r * 32 + kk0;
        if (m >= n) {                    // pad row -> exact zeros (avoid NaN in MFMA)
            if (h == 0) {
                #pragma unroll
                for (int d = 0; d < DWN; ++d) ((uint*)ap)[d] = 0;
            }
            continue;
        }
        vec_t sv = *(const vec_t*)(gofs + (size_t)m * FIN);
        float self[EPT], acc[EPT];
        #pragma unroll
        for (int d = 0; d < DWN; ++d) {
            uint dw = ((const uint*)&sv)[d];
            self[2 * d]     = __uint_as_float(dw << 16);
            self[2 * d + 1] = __uint_as_float(dw & 0xffff0000u);
        }
        #pragma unroll
        for (int t = 0; t < EPT; ++t) acc[t] = 0.f;

        int e0 = rowptr[m];
        int deg = rowptr[m + 1] - e0;
        for (int base = 0; base < deg; base += 64) {
            int cnt = min(64, deg - base);
            int ec = (lane < cnt) ? col[e0 + base + lane] : zrow;  // pad lanes -> zero row
            for (int j = 0; j < cnt; j += 16) {
                vec_t v[8];
                #pragma unroll
                for (int u = 0; u < 8; ++u) {
                    int id = __shfl(ec, j + u * 2 + h);
                    v[u] = *(const vec_t*)(gofs + (size_t)id * FIN);
                }
                #pragma unroll
                for (int u = 0; u < 8; ++u)
                    #pragma unroll
                    for (int d = 0; d < DWN; ++d) {
                        uint dw = ((const uint*)&v[u])[d];
                        acc[2 * d]     += __uint_as_float(dw << 16);
                        acc[2 * d + 1] += __uint_as_float(dw & 0xffff0000u);
                    }
            }
        }
        #pragma unroll
        for (int t = 0; t < EPT; ++t) acc[t] += __shfl_xor(acc[t], 32, 64);

        if (h == 0) {
            float di = dinv[m];
            uint pk[DWN];
            #pragma unroll
            for (int d = 0; d < DWN; ++d) {
                float r0 = fmaxf(di * (acc[2 * d]     + self[2 * d])     + bias[off + 2 * d],     0.f);
                float r1 = fmaxf(di * (acc[2 * d + 1] + self[2 * d + 1]) + bias[off + 2 * d + 1], 0.f);
                pk[d] = (uint)f2bf(r0) | ((uint)f2bf(r1) << 16);
            }
            #pragma unroll
            for (int d = 0; d < DWN; ++d) ((uint*)ap)[d] = pk[d];
        }
    }
    __syncthreads();

    // ---- phase 2: C[64 x NOUT] = dinv .* (A @ Bt^T) ----
    constexpr int WC = NOUT / 32;        // waves across N (4 or 2)
    constexpr int WR = 8 / WC;           // waves across M (2 or 4)
    constexpr int MI = 64 / WR / 16;     // 16-row frags per wave (2 or 1)
    int wr = wv / WC, wc = wv % WC;
    int quad = lane >> 4, l15 = lane & 15;
    float4_t acc2[MI][2];
    #pragma unroll
    for (int i = 0; i < MI; ++i) {
        acc2[i][0] = (float4_t)0.f;
        acc2[i][1] = (float4_t)0.f;
    }
    int arowb = wr * (MI * 16) + l15;
    const ushort* bp = Bt + (size_t)(wc * 32 + l15) * FIN + quad * 8;
    #pragma unroll
    for (int c = 0; c < NCH; ++c) {
        short8_t aF[MI], bF[2];
        #pragma unroll
        for (int i = 0; i < MI; ++i)
            aF[i] = *(const short8_t*)&As[c * 2048 + (arowb + i * 16) * 32 + quad * 8];
        #pragma unroll
        for (int j = 0; j < 2; ++j)
            bF[j] = *(const short8_t*)(bp + (size_t)(j * 16) * FIN + c * 32);
        #pragma unroll
        for (int i = 0; i < MI; ++i) {
            acc2[i][0] = __builtin_amdgcn_mfma_f32_16x16x32_bf16(aF[i], bF[0], acc2[i][0], 0, 0, 0);
            acc2[i][1] = __builtin_amdgcn_mfma_f32_16x16x32_bf16(aF[i], bF[1], acc2[i][1], 0, 0, 0);
        }
    }
    #pragma unroll
    for (int i = 0; i < MI; ++i) {
        int mb = bm + wr * (MI * 16) + i * 16 + quad * 4;
        #pragma unroll
        for (int rr = 0; rr < 4; ++rr) {
            int m = mb + rr;
            float s = dinv[m];
            #pragma unroll
            for (int j = 0; j < 2; ++j) {
                int ncol = wc * 32 + j * 16 + l15;
                C[(size_t)m * NOUT + ncol] = f2bf(acc2[i][j][rr] * s);
            }
        }
    }
}

// ---------------- standalone agg (layer 3, F=64, bf16) ----------------
template <int F, bool RELU>
__global__ __launch_bounds__(256) void agg_bf(const ushort* __restrict__ g,
                                              const int* __restrict__ rowptr,
                                              const int* __restrict__ col,
                                              const float* __restrict__ dinv,
                                              const float* __restrict__ bias,
                                              ushort* __restrict__ out,
                                              int n, int npad, int zrow) {
    constexpr int EPL  = (F == 64) ? 4 : 2;  // edges per load instruction
    constexpr int SUBW = 64 / EPL;           // lanes per edge
    constexpr int EPT  = F / SUBW;           // elements per lane
    constexpr int LPG  = 16 / EPL;           // loads per 16-edge flight group
    constexpr int DWN  = EPT / 2;            // dwords per load
    using vec_t = typename VecT<DWN>::type;

    int wid = (int)((blockIdx.x * blockDim.x + threadIdx.x) >> 6);
    int lane = threadIdx.x & 63;
    if (wid >= npad) return;
    int h   = lane / SUBW;
    int sub = lane & (SUBW - 1);
    int off = sub * EPT;
    ushort* orow = out + (size_t)wid * F + off;

    if (wid >= n) {  // zero padded tail rows
        if (h == 0) {
            #pragma unroll
            for (int d = 0; d < DWN; ++d) ((uint*)orow)[d] = 0;
        }
        return;
    }

    const ushort* gofs = g + off;
    vec_t sv = *(const vec_t*)(gofs + (size_t)wid * F);
    float self[EPT];
    #pragma unroll
    for (int d = 0; d < DWN; ++d) {
        uint dw = ((const uint*)&sv)[d];
        self[2 * d]     = __uint_as_float(dw << 16);
        self[2 * d + 1] = __uint_as_float(dw & 0xffff0000u);
    }

    float acc[EPT];
    #pragma unroll
    for (int t = 0; t < EPT; ++t) acc[t] = 0.f;

    int e0 = rowptr[wid];
    int deg = rowptr[wid + 1] - e0;

    for (int base = 0; base < deg; base += 64) {
        int cnt = min(64, deg - base);
        int ec = (lane < cnt) ? col[e0 + base + lane] : zrow;
        for (int j = 0; j < cnt; j += 16) {
            vec_t v[LPG];
            #pragma unroll
            for (int u = 0; u < LPG; ++u) {
                int id = __shfl(ec, j + u * EPL + h);
                v[u] = *(const vec_t*)(gofs + (size_t)id * F);
            }
            #pragma unroll
            for (int u = 0; u < LPG; ++u)
                #pragma unroll
                for (int d = 0; d < DWN; ++d) {
                    uint dw = ((const uint*)&v[u])[d];
                    acc[2 * d]     += __uint_as_float(dw << 16);
                    acc[2 * d + 1] += __uint_as_float(dw & 0xffff0000u);
                }
        }
    }

    #pragma unroll
    for (int t = 0; t < EPT; ++t) {
        if constexpr (EPL == 4) acc[t] += __shfl_xor(acc[t], 16, 64);
        acc[t] += __shfl_xor(acc[t], 32, 64);
    }

    float di = dinv[wid];
    ushort res[EPT];
    #pragma unroll
    for (int t = 0; t < EPT; ++t) {
        float r = di * (acc[t] + self[t]) + bias[off + t];
        if (RELU) r = fmaxf(r, 0.f);
        res[t] = f2bf(r);
    }
    if (h == 0) {
        #pragma unroll
        for (int d = 0; d < DWN; ++d)
            ((uint*)orow)[d] = (uint)res[2 * d] | ((uint)res[2 * d + 1] << 16);
    }
}

// ---------------- pooling + final linear ----------------

__global__ __launch_bounds__(256) void pool_sorted(const ushort* __restrict__ h,
                                                   const int* __restrict__ batch,
                                                   float* __restrict__ sums,
                                                   float* __restrict__ cnt, int n) {
    int wave = (int)((blockIdx.x * blockDim.x + threadIdx.x) >> 6);
    int lane = threadIdx.x & 63;
    int start = wave * 64;
    if (start >= n) return;
    int end = min(start + 64, n);
    float acc = 0.f;
    int cur = batch[start];
    int runlen = 0;
    for (int i = start; i < end; ++i) {
        int b = batch[i];
        if (b != cur) {
            atomicAdd(&sums[cur * 64 + lane], acc);
            if (lane == 0) atomicAdd(&cnt[cur], (float)runlen);
            acc = 0.f;
            runlen = 0;
            cur = b;
        }
        acc += bf2f(h[(size_t)i * 64 + lane]);
        runlen++;
    }
    atomicAdd(&sums[cur * 64 + lane], acc);
    if (lane == 0) atomicAdd(&cnt[cur], (float)runlen);
}

__global__ void final_lin(const float* __restrict__ sums, const float* __restrict__ cnt,
                          const float* __restrict__ Wl, const float* __restrict__ bl,
                          float* __restrict__ out) {
    int t = threadIdx.x;  // 128 threads: (graph, j)
    int g = t >> 1, j = t & 1;
    float c = fmaxf(cnt[g], 1.0f);
    float a = 0.f;
    #pragma unroll
    for (int k = 0; k < 64; ++k) a += sums[g * 64 + k] * Wl[k * 2 + j];
    out[t] = a / c + bl[j];
}

// ---------------- launch ----------------

extern "C" void kernel_launch(void* const* d_in, const int* in_sizes, int n_in,
                              void* d_out, int out_size, void* d_ws, size_t ws_size,
                              hipStream_t stream) {
    const float* x   = (const float*)d_in[0];
    const int*   ei  = (const int*)d_in[1];
    const int*   bat = (const int*)d_in[2];
    const float* W1  = (const float*)d_in[3];
    const float* b1  = (const float*)d_in[4];
    const float* W2  = (const float*)d_in[5];
    const float* b2  = (const float*)d_in[6];
    const float* W3  = (const float*)d_in[7];
    const float* b3  = (const float*)d_in[8];
    const float* Wl  = (const float*)d_in[9];
    const float* bl  = (const float*)d_in[10];
    float* out = (float*)d_out;

    const int N = in_sizes[0] / 512;
    const int E = in_sizes[1] / 2;
    const int Mpad = ((N + 127) / 128) * 128;   // 50048
    const int* src = ei;
    const int* dst = ei + E;

    char* w = (char*)d_ws;
    auto alloc = [&](size_t bytes) {
        char* p = w;
        w += (bytes + 255) & ~(size_t)255;
        return p;
    };
    ushort* Xb   = (ushort*)alloc((size_t)Mpad * 512 * 2);  // bf16 x
    ushort* G1   = (ushort*)alloc((size_t)Mpad * 256 * 2);  // gemm1 out / agg1 gather src
    ushort* G2   = (ushort*)alloc((size_t)Mpad * 128 * 2);  // k5 out / agg2 gather src
    ushort* G3   = (ushort*)alloc((size_t)Mpad * 64 * 2);   // k6 out / agg3 gather src
    ushort* H3   = (ushort*)alloc((size_t)Mpad * 64 * 2);   // agg3 out (pool input)
    ushort* Wt1  = (ushort*)alloc(256 * 512 * 2);
    ushort* Wt2  = (ushort*)alloc(128 * 256 * 2);
    ushort* Wt3  = (ushort*)alloc(64 * 128 * 2);
    float* dinv  = (float*)alloc((size_t)Mpad * 4);
    int* rowptr  = (int*)alloc((size_t)(N + 1) * 4);
    int* cursor8 = (int*)alloc((size_t)8 * Mpad * 4);
    int* col     = (int*)alloc((size_t)(E + 16) * 4);
    int* part    = (int*)alloc(256 * 4);
    int nzero = 8 * Mpad + 64 * 64 + 64;        // indeg8 + sums + cnt
    int* indeg8  = (int*)alloc((size_t)nzero * 4);
    float* sums  = (float*)(indeg8 + 8 * Mpad);
    float* cnt   = sums + 64 * 64;

    // k0: zero indeg8 + sums + cnt
    zero_k<<<(nzero + 255) / 256, 256, 0, stream>>>(indeg8, nzero);

    // k1: conv_x ∥ weights ∥ count (interleaved: every 9th block = count)
    int nxblk = (Mpad * 128) / 256;             // conv_x blocks (t = float4 index)
    int ncblk = (E + 255) / 256;                // 3125 count/fill edge-blocks
    int others = nxblk + 672;
    int T = (others * 9) / 8 + 9;               // enough slots for both roles
    prep<<<T, 256, 0, stream>>>(x, Xb, W1, Wt1, W2, Wt2, W3, Wt3,
                                dst, indeg8, N, Mpad, E, nxblk, ncblk);

    // CSR scan
    int nb = (N + 1023) / 1024;
    scan1<<<nb, 1024, 0, stream>>>(indeg8, rowptr, part, N, Mpad);
    scan23<<<(Mpad + 255) / 256, 256, 0, stream>>>(indeg8, rowptr, cursor8, part, dinv,
                                                   N, Mpad, E, nb);

    // fill_csr (8-sliced cursors; same edge-block->copy mapping as count)
    fill_csr<<<ncblk, 256, 0, stream>>>(src, dst, cursor8, col, E, Mpad);

    // gemm1 (512->256)
    gemm1<<<(Mpad / 128) * 2, 256, 0, stream>>>(Xb, Wt1, dinv, G1);

    // k5: agg1 (relu, b1) + gemm2 (256->128) fused, BM=64
    agg_gemm<256, 128><<<Mpad / 64, 512, 0, stream>>>(G1, rowptr, col, dinv, b1,
                                                      Wt2, G2, N, N);
    // k6: agg2 (relu, b2) + gemm3 (128->64) fused, BM=64
    agg_gemm<128, 64><<<Mpad / 64, 512, 0, stream>>>(G2, rowptr, col, dinv, b2,
                                                     Wt3, G3, N, N);
    // agg3 (b3, no relu)
    agg_bf<64, false><<<Mpad / 4, 256, 0, stream>>>(G3, rowptr, col, dinv, b3, H3,
                                                    N, Mpad, N);

    pool_sorted<<<(N + 255) / 256, 256, 0, stream>>>(H3, bat, sums, cnt, N);
    final_lin<<<1, 128, 0, stream>>>(sums, cnt, Wl, bl, out);
}

// Round 9
// 395.828 us; speedup vs baseline: 1.1670x; 1.0689x over previous
//
#include <hip/hip_runtime.h>
#include <hip/hip_fp16.h>

// GCN: 3x gcn_conv + mean-pool + linear, bf16 MFMA pipeline, fused layers.
// out[i] = dinv[i] * (sum_{e: dst=i} g[src_e] + g[i]) + b,  g = dinv .* (x @ W)
// Structure: k0 zero -> k1 prep(conv_x ∥ weights ∥ count, interleaved) -> scan1
//   -> scan23 -> fill_csr -> gemm1 -> k5 agg1+gemm2 (BM=64) -> k6 agg2+gemm3
//   -> agg3 -> pool -> final.
// R8 diagnosis: agg_gemm is FETCH-bound (185MB @ 2.4TB/s = dur; 7.05 XCDs/row
// L2-fill floor). -> G1/G2/G3 stored fp8 e4m3: halves row bytes AND line count.
// Decode via v_cvt_pk_f32_fp8 (fallback f16 bit-trick, x256 folded into dinv).

typedef __attribute__((ext_vector_type(8))) short short8_t;
typedef __attribute__((ext_vector_type(4))) float float4_t;
typedef __attribute__((ext_vector_type(2))) float float2_t;

__device__ __forceinline__ unsigned short f2bf(float f) {
    unsigned int u = __float_as_uint(f);
    u += 0x7FFFu + ((u >> 16) & 1u);   // round-to-nearest-even
    return (unsigned short)(u >> 16);
}
__device__ __forceinline__ float bf2f(unsigned short h) {
    return __uint_as_float(((unsigned int)h) << 16);
}

// ---- fp8 e4m3fn encode (epilogue-only; RNE via f16 bit trick; sat to 448) ----
__device__ __forceinline__ unsigned char f2fp8(float v) {
    unsigned short h = __half_as_ushort(__float2half(v * 0.00390625f));  // v*2^-8, RNE
    unsigned int mag = h & 0x7fffu;
    unsigned int r = (mag + 0x3Fu + ((h >> 7) & 1u)) >> 7;               // RNE to 3-bit mant
    if (r > 0x7eu) r = 0x7eu;
    return (unsigned char)(((h >> 8) & 0x80u) | r);
}

// ---- fp8 decode in the gather hot loop: 4 feats per dword ----
#if __has_builtin(__builtin_amdgcn_cvt_pk_f32_fp8)
#define DEC_SCALE 1.0f
__device__ __forceinline__ void f8x4_acc(unsigned int dw, float* a) {
    float2_t lo = __builtin_amdgcn_cvt_pk_f32_fp8((int)dw, false);
    float2_t hi = __builtin_amdgcn_cvt_pk_f32_fp8((int)dw, true);
    a[0] += lo[0]; a[1] += lo[1]; a[2] += hi[0]; a[3] += hi[1];
}
#else
#define DEC_SCALE 256.0f  // decoded values are true/256; folded into dinv
__device__ __forceinline__ void f8x4_acc(unsigned int dw, float* a) {
    #pragma unroll
    for (int b = 0; b < 4; ++b) {
        unsigned int x = (dw >> (8 * b)) & 0xffu;
        unsigned short hb = (unsigned short)(((x & 0x80u) << 8) | ((x & 0x7fu) << 7));
        a[b] += __half2float(__ushort_as_half(hb));
    }
}
#endif

// async global->LDS, 16B per lane; LDS dest is wave-uniform base + lane*16
#define GLDS16(gp, lp)                                                          \
    __builtin_amdgcn_global_load_lds(                                           \
        (const __attribute__((address_space(1))) void*)(gp),                    \
        (__attribute__((address_space(3))) void*)(lp), 16, 0, 0)

template <int NDW> struct VecT;
template <> struct VecT<1> { using type = uint; };
template <> struct VecT<2> { using type = uint2; };

// ---------------- k0: zero indeg8 + sums + cnt ----------------
__global__ void zero_k(int* __restrict__ p, int n) {
    int i = blockIdx.x * blockDim.x + threadIdx.x;
    if (i < n) p[i] = 0;
}

// ---------------- k1: conv_x ∥ weights ∥ count_indeg, interleaved ----------------
__global__ __launch_bounds__(256) void prep(const float* __restrict__ x,
                                            ushort* __restrict__ Xb,
                                            const float* __restrict__ W1, ushort* __restrict__ Wt1,
                                            const float* __restrict__ W2, ushort* __restrict__ Wt2,
                                            const float* __restrict__ W3, ushort* __restrict__ Wt3,
                                            const int* __restrict__ dst, int* __restrict__ indeg8,
                                            int M, int Mpad, int E, int nxblk, int ncblk) {
    int bx = blockIdx.x;
    if ((bx % 9) == 8) {                     // count_indeg, 8-way sliced by edge-block
        int cb = bx / 9;                     // edge-block index (matches fill_csr's)
        if (cb < ncblk) {
            int t = cb * 256 + threadIdx.x;
            if (t < E) atomicAdd(&indeg8[(size_t)(cb & 7) * Mpad + dst[t]], 1);
        }
        return;
    }
    int ox = bx - (bx + 1) / 9;              // non-count index
    if (ox < nxblk) {                        // conv_x: fp32 x -> bf16 Xb (padded)
        int t = ox * 256 + threadIdx.x;      // one float4 -> ushort4
        int row = t >> 7;
        ushort4 o;
        if (row < M) {
            float4 v = ((const float4*)x)[t];
            o.x = f2bf(v.x); o.y = f2bf(v.y); o.z = f2bf(v.z); o.w = f2bf(v.w);
        } else {
            o.x = o.y = o.z = o.w = 0;
        }
        if (row < Mpad) ((ushort4*)Xb)[t] = o;
    } else {                                 // weight transpose+convert (172032 elems)
        int t = (ox - nxblk) * 256 + threadIdx.x;
        if (t < 131072) {                    // Wt1 [256][512]
            int k = t & 511, nn = t >> 9;
            Wt1[t] = f2bf(W1[(size_t)k * 256 + nn]);
        } else if (t < 163840) {             // Wt2 [128][256]
            int u = t - 131072;
            int k = u & 255, nn = u >> 8;
            Wt2[u] = f2bf(W2[(size_t)k * 128 + nn]);
        } else if (t < 172032) {             // Wt3 [64][128]
            int u = t - 163840;              // [0, 8192)
            int k = u & 127, nn = u >> 7;    // nn < 64
            Wt3[u] = f2bf(W3[(size_t)k * 64 + nn]);
        }
    }
}

// ---------------- CSR scan ----------------
__global__ __launch_bounds__(1024) void scan1(const int* __restrict__ indeg8,
                                              int* __restrict__ incl,   // rowptr as temp
                                              int* __restrict__ part, int n, int Mpad) {
    __shared__ int sm[1024];
    int i = blockIdx.x * 1024 + threadIdx.x;
    int v = 0;
    if (i < n) {
        #pragma unroll
        for (int c = 0; c < 8; ++c) v += indeg8[(size_t)c * Mpad + i];
    }
    sm[threadIdx.x] = v;
    __syncthreads();
    #pragma unroll
    for (int off = 1; off < 1024; off <<= 1) {
        int t = (threadIdx.x >= (unsigned)off) ? sm[threadIdx.x - off] : 0;
        __syncthreads();
        sm[threadIdx.x] += t;
        __syncthreads();
    }
    if (i < n) incl[i] = sm[threadIdx.x];
    if (threadIdx.x == 1023) part[blockIdx.x] = sm[1023];
}

__global__ __launch_bounds__(256) void scan23(const int* __restrict__ indeg8,
                                              int* __restrict__ rowptr,
                                              int* __restrict__ cursor8,
                                              const int* __restrict__ part,
                                              float* __restrict__ dinv,
                                              int n, int npad, int E, int nb) {
    __shared__ int ps[64];
    int tid = threadIdx.x;
    if (tid < 64) {
        int v = (tid < nb) ? part[tid] : 0;
        int orig = v;
        #pragma unroll
        for (int off = 1; off < 64; off <<= 1) {
            int u = __shfl_up(v, off, 64);
            if (tid >= off) v += u;
        }
        ps[tid] = v - orig;  // exclusive chunk offset
    }
    __syncthreads();
    int i = blockIdx.x * 256 + tid;
    if (i < n) {
        int d8[8], deg = 0;
        #pragma unroll
        for (int c = 0; c < 8; ++c) {
            d8[c] = indeg8[(size_t)c * npad + i];
            deg += d8[c];
        }
        int excl = rowptr[i] - deg + ps[i >> 10];
        rowptr[i] = excl;
        int run = excl;
        #pragma unroll
        for (int c = 0; c < 8; ++c) {        // per-copy exclusive cursors
            cursor8[(size_t)c * npad + i] = run;
            run += d8[c];
        }
        dinv[i] = rsqrtf((float)deg + 1.0f); // +1 self-loop
    } else if (i < npad) {
        dinv[i] = 0.f;                       // pad rows -> C rows are exact 0
    }
    if (i == 0) rowptr[n] = E;
}

// ---------------- fill_csr: 8-sliced cursors (same edge-block mapping as count) ----------------
__global__ void fill_csr(const int* __restrict__ src, const int* __restrict__ dst,
                         int* __restrict__ cursor8, int* __restrict__ col,
                         int E, int Mpad) {
    int bx = blockIdx.x;
    int e = bx * 256 + threadIdx.x;
    if (e < E) {
        int p = atomicAdd(&cursor8[(size_t)(bx & 7) * Mpad + dst[e]], 1);
        col[p] = src[e];
    }
}

// ---------------- gemm1 (K=512, N=256), 128x128 tile, fp8 output ----------------
__global__ __launch_bounds__(256) void gemm1(const ushort* __restrict__ A,
                                             const ushort* __restrict__ Bt,
                                             const float* __restrict__ dinv,
                                             unsigned char* __restrict__ C) {
    __shared__ __align__(16) ushort As[2 * 4096];
    __shared__ __align__(16) ushort Bs[2 * 4096];
    constexpr int K = 512;
    int bx = blockIdx.x;
    int tid = threadIdx.x;
    int lane = tid & 63, w = tid >> 6;
    int wr = w >> 1, wc = w & 1;
    int bm = (bx >> 1) * 128, bn = (bx & 1) * 128;

    float4_t acc[4][4];
    #pragma unroll
    for (int i = 0; i < 4; ++i)
        #pragma unroll
        for (int j = 0; j < 4; ++j) acc[i][j] = (float4_t)0.0f;

    int r0 = tid >> 2;
    int kb = (tid & 3) * 8;
    const ushort* ga0 = A + (size_t)(bm + r0) * K + kb;
    const ushort* ga1 = A + (size_t)(bm + r0 + 64) * K + kb;
    const ushort* gb0 = Bt + (size_t)(bn + r0) * K + kb;
    const ushort* gb1 = Bt + (size_t)(bn + r0 + 64) * K + kb;
    int w512 = w * 512;

#define ISSUE_DMA(kk, bufofs)                              \
    do {                                                   \
        GLDS16(ga0 + (kk), As + (bufofs) + w512);          \
        GLDS16(ga1 + (kk), As + (bufofs) + 2048 + w512);   \
        GLDS16(gb0 + (kk), Bs + (bufofs) + w512);          \
        GLDS16(gb1 + (kk), Bs + (bufofs) + 2048 + w512);   \
    } while (0)

    int arow = wr * 64 + (lane & 15);
    int brow = wc * 64 + (lane & 15);
    int quad = lane >> 4;

    ISSUE_DMA(0, 0);  // prologue -> buf0
    for (int k0 = 0; k0 < K; k0 += 64) {
        __syncthreads();
        ISSUE_DMA(k0 + 32, 4096);
        {
            short8_t aF[4], bF[4];
            #pragma unroll
            for (int i = 0; i < 4; ++i)
                aF[i] = *(const short8_t*)&As[(arow + i * 16) * 32 + quad * 8];
            #pragma unroll
            for (int j = 0; j < 4; ++j)
                bF[j] = *(const short8_t*)&Bs[(brow + j * 16) * 32 + quad * 8];
            #pragma unroll
            for (int i = 0; i < 4; ++i)
                #pragma unroll
                for (int j = 0; j < 4; ++j)
                    acc[i][j] = __builtin_amdgcn_mfma_f32_16x16x32_bf16(aF[i], bF[j], acc[i][j], 0, 0, 0);
        }
        __syncthreads();
        if (k0 + 64 < K) ISSUE_DMA(k0 + 64, 0);
        {
            short8_t aF[4], bF[4];
            #pragma unroll
            for (int i = 0; i < 4; ++i)
                aF[i] = *(const short8_t*)&As[4096 + (arow + i * 16) * 32 + quad * 8];
            #pragma unroll
            for (int j = 0; j < 4; ++j)
                bF[j] = *(const short8_t*)&Bs[4096 + (brow + j * 16) * 32 + quad * 8];
            #pragma unroll
            for (int i = 0; i < 4; ++i)
                #pragma unroll
                for (int j = 0; j < 4; ++j)
                    acc[i][j] = __builtin_amdgcn_mfma_f32_16x16x32_bf16(aF[i], bF[j], acc[i][j], 0, 0, 0);
        }
    }
#undef ISSUE_DMA

    // C/D layout: col = lane&15, row = (lane>>4)*4 + reg
    int colb = bn + wc * 64 + (lane & 15);
    #pragma unroll
    for (int i = 0; i < 4; ++i) {
        int mb = bm + wr * 64 + i * 16 + quad * 4;
        #pragma unroll
        for (int r = 0; r < 4; ++r) {
            int m = mb + r;
            float s = dinv[m];
            #pragma unroll
            for (int j = 0; j < 4; ++j) {
                int n = colb + j * 16;
                C[(size_t)m * 256 + n] = f2fp8(acc[i][j][r] * s);
            }
        }
    }
}

// ---------------- fused agg + gemm: block owns 64 rows; fp8 gather in/out ----------------
// Phase 1: 8 waves aggregate 8 rows each (fp8 gather from g, CSR), apply
//   dinv(+DEC_SCALE)/bias/relu, write bf16 A-tile into LDS k-chunks.
// Phase 2: 64xNOUT MFMA, B from global (L2-resident); epilogue writes fp8 C.
template <int FIN, int NOUT>
__global__ __launch_bounds__(512) void agg_gemm(const unsigned char* __restrict__ g,
                                                const int* __restrict__ rowptr,
                                                const int* __restrict__ col,
                                                const float* __restrict__ dinv,
                                                const float* __restrict__ bias,
                                                const ushort* __restrict__ Bt,   // [NOUT][FIN]
                                                unsigned char* __restrict__ C,   // [Mpad][NOUT] fp8
                                                int n, int zrow) {
    constexpr int NCH = FIN / 32;        // LDS k-chunks
    constexpr int EPT = FIN / 32;        // feats per lane (32 lanes/row)
    constexpr int NDW = EPT / 4;         // dwords per fp8 gather load (2 or 1)
    constexpr int SDW = EPT / 2;         // bf16 dwords per LDS store
    using vec_t = typename VecT<NDW>::type;
    __shared__ __align__(16) ushort As[NCH * 64 * 32];    // 32KB / 16KB

    int tid = threadIdx.x;
    int lane = tid & 63, wv = tid >> 6;  // 8 waves
    int bm = blockIdx.x * 64;
    int h = lane >> 5, sub = lane & 31;  // 2 edge slots x 32 lanes/row
    int off = sub * EPT;
    const unsigned char* gofs = g + off;
    int cch0 = off >> 5, kk0 = off & 31;

    // ---- phase 1: aggregate (8 rows per wave) ----
    for (int q = 0; q < 8; ++q) {
        int r = wv * 8 + q;
        int m = bm + r;
        ushort* ap = As + cch0 * 2048 + r * 32 + kk0;
        if (m >= n) {                    // pad row -> exact zeros
            if (h == 0) {
                #pragma unroll
                for (int d = 0; d < SDW; ++d) ((uint*)ap)[d] = 0;
            }
            continue;
        }
        vec_t sv = *(const vec_t*)(gofs + (size_t)m * FIN);
        float self[EPT], acc[EPT];
        #pragma unroll
        for (int t = 0; t < EPT; ++t) { self[t] = 0.f; acc[t] = 0.f; }
        #pragma unroll
        for (int d = 0; d < NDW; ++d) f8x4_acc(((const uint*)&sv)[d], self + 4 * d);

        int e0 = rowptr[m];
        int deg = rowptr[m + 1] - e0;
        for (int base = 0; base < deg; base += 64) {
            int cnt = min(64, deg - base);
            int ec = (lane < cnt) ? col[e0 + base + lane] : zrow;  // pad lanes -> zero row
            for (int j = 0; j < cnt; j += 16) {
                vec_t v[8];
                #pragma unroll
                for (int u = 0; u < 8; ++u) {
                    int id = __shfl(ec, j + u * 2 + h);
                    v[u] = *(const vec_t*)(gofs + (size_t)id * FIN);
                }
                #pragma unroll
                for (int u = 0; u < 8; ++u)
                    #pragma unroll
                    for (int d = 0; d < NDW; ++d)
                        f8x4_acc(((const uint*)&v[u])[d], acc + 4 * d);
            }
        }
        #pragma unroll
        for (int t = 0; t < EPT; ++t) acc[t] += __shfl_xor(acc[t], 32, 64);

        if (h == 0) {
            float di = dinv[m] * DEC_SCALE;
            uint pk[SDW];
            #pragma unroll
            for (int d = 0; d < SDW; ++d) {
                float r0 = fmaxf(di * (acc[2 * d]     + self[2 * d])     + bias[off + 2 * d],     0.f);
                float r1 = fmaxf(di * (acc[2 * d + 1] + self[2 * d + 1]) + bias[off + 2 * d + 1], 0.f);
                pk[d] = (uint)f2bf(r0) | ((uint)f2bf(r1) << 16);
            }
            #pragma unroll
            for (int d = 0; d < SDW; ++d) ((uint*)ap)[d] = pk[d];
        }
    }
    __syncthreads();

    // ---- phase 2: C[64 x NOUT] = fp8( dinv .* (A @ Bt^T) ) ----
    constexpr int WC = NOUT / 32;        // waves across N (4 or 2)
    constexpr int WR = 8 / WC;           // waves across M (2 or 4)
    constexpr int MI = 64 / WR / 16;     // 16-row frags per wave (2 or 1)
    int wr = wv / WC, wc = wv % WC;
    int quad = lane >> 4, l15 = lane & 15;
    float4_t acc2[MI][2];
    #pragma unroll
    for (int i = 0; i < MI; ++i) {
        acc2[i][0] = (float4_t)0.f;
        acc2[i][1] = (float4_t)0.f;
    }
    int arowb = wr * (MI * 16) + l15;
    const ushort* bp = Bt + (size_t)(wc * 32 + l15) * FIN + quad * 8;
    #pragma unroll
    for (int c = 0; c < NCH; ++c) {
        short8_t aF[MI], bF[2];
        #pragma unroll
        for (int i = 0; i < MI; ++i)
            aF[i] = *(const short8_t*)&As[c * 2048 + (arowb + i * 16) * 32 + quad * 8];
        #pragma unroll
        for (int j = 0; j < 2; ++j)
            bF[j] = *(const short8_t*)(bp + (size_t)(j * 16) * FIN + c * 32);
        #pragma unroll
        for (int i = 0; i < MI; ++i) {
            acc2[i][0] = __builtin_amdgcn_mfma_f32_16x16x32_bf16(aF[i], bF[0], acc2[i][0], 0, 0, 0);
            acc2[i][1] = __builtin_amdgcn_mfma_f32_16x16x32_bf16(aF[i], bF[1], acc2[i][1], 0, 0, 0);
        }
    }
    #pragma unroll
    for (int i = 0; i < MI; ++i) {
        int mb = bm + wr * (MI * 16) + i * 16 + quad * 4;
        #pragma unroll
        for (int rr = 0; rr < 4; ++rr) {
            int m = mb + rr;
            float s = dinv[m];
            #pragma unroll
            for (int j = 0; j < 2; ++j) {
                int ncol = wc * 32 + j * 16 + l15;
                C[(size_t)m * NOUT + ncol] = f2fp8(acc2[i][j][rr] * s);
            }
        }
    }
}

// ---------------- standalone agg (layer 3, F=64): fp8 in / bf16 out ----------------
__global__ __launch_bounds__(256) void agg3_f8(const unsigned char* __restrict__ g,
                                               const int* __restrict__ rowptr,
                                               const int* __restrict__ col,
                                               const float* __restrict__ dinv,
                                               const float* __restrict__ bias,
                                               ushort* __restrict__ out,
                                               int n, int npad, int zrow) {
    int wid = (int)((blockIdx.x * blockDim.x + threadIdx.x) >> 6);
    int lane = threadIdx.x & 63;
    if (wid >= npad) return;
    int h   = lane >> 4;                 // 4 edge slots
    int sub = lane & 15;                 // 16 lanes/row
    int off = sub * 4;                   // 4 feats/lane
    ushort* orow = out + (size_t)wid * 64 + off;

    if (wid >= n) {  // zero padded tail rows
        if (h == 0) { ((uint*)orow)[0] = 0; ((uint*)orow)[1] = 0; }
        return;
    }

    const unsigned char* gofs = g + off;
    uint sv = *(const uint*)(gofs + (size_t)wid * 64);
    float self[4] = {0.f, 0.f, 0.f, 0.f};
    f8x4_acc(sv, self);

    float acc[4] = {0.f, 0.f, 0.f, 0.f};
    int e0 = rowptr[wid];
    int deg = rowptr[wid + 1] - e0;

    for (int base = 0; base < deg; base += 64) {
        int cnt = min(64, deg - base);
        int ec = (lane < cnt) ? col[e0 + base + lane] : zrow;
        for (int j = 0; j < cnt; j += 16) {
            uint v[4];
            #pragma unroll
            for (int u = 0; u < 4; ++u) {
                int id = __shfl(ec, j + u * 4 + h);
                v[u] = *(const uint*)(gofs + (size_t)id * 64);
            }
            #pragma unroll
            for (int u = 0; u < 4; ++u) f8x4_acc(v[u], acc);
        }
    }

    #pragma unroll
    for (int t = 0; t < 4; ++t) {
        acc[t] += __shfl_xor(acc[t], 16, 64);
        acc[t] += __shfl_xor(acc[t], 32, 64);
    }

    float dis = dinv[wid] * DEC_SCALE;
    ushort res[4];
    #pragma unroll
    for (int t = 0; t < 4; ++t)
        res[t] = f2bf(dis * (acc[t] + self[t]) + bias[off + t]);   // no relu
    if (h == 0) {
        ((uint*)orow)[0] = (uint)res[0] | ((uint)res[1] << 16);
        ((uint*)orow)[1] = (uint)res[2] | ((uint)res[3] << 16);
    }
}

// ---------------- pooling + final linear ----------------

__global__ __launch_bounds__(256) void pool_sorted(const ushort* __restrict__ h,
                                                   const int* __restrict__ batch,
                                                   float* __restrict__ sums,
                                                   float* __restrict__ cnt, int n) {
    int wave = (int)((blockIdx.x * blockDim.x + threadIdx.x) >> 6);
    int lane = threadIdx.x & 63;
    int start = wave * 64;
    if (start >= n) return;
    int end = min(start + 64, n);
    float acc = 0.f;
    int cur = batch[start];
    int runlen = 0;
    for (int i = start; i < end; ++i) {
        int b = batch[i];
        if (b != cur) {
            atomicAdd(&sums[cur * 64 + lane], acc);
            if (lane == 0) atomicAdd(&cnt[cur], (float)runlen);
            acc = 0.f;
            runlen = 0;
            cur = b;
        }
        acc += bf2f(h[(size_t)i * 64 + lane]);
        runlen++;
    }
    atomicAdd(&sums[cur * 64 + lane], acc);
    if (lane == 0) atomicAdd(&cnt[cur], (float)runlen);
}

__global__ void final_lin(const float* __restrict__ sums, const float* __restrict__ cnt,
                          const float* __restrict__ Wl, const float* __restrict__ bl,
                          float* __restrict__ out) {
    int t = threadIdx.x;  // 128 threads: (graph, j)
    int g = t >> 1, j = t & 1;
    float c = fmaxf(cnt[g], 1.0f);
    float a = 0.f;
    #pragma unroll
    for (int k = 0; k < 64; ++k) a += sums[g * 64 + k] * Wl[k * 2 + j];
    out[t] = a / c + bl[j];
}

// ---------------- launch ----------------

extern "C" void kernel_launch(void* const* d_in, const int* in_sizes, int n_in,
                              void* d_out, int out_size, void* d_ws, size_t ws_size,
                              hipStream_t stream) {
    const float* x   = (const float*)d_in[0];
    const int*   ei  = (const int*)d_in[1];
    const int*   bat = (const int*)d_in[2];
    const float* W1  = (const float*)d_in[3];
    const float* b1  = (const float*)d_in[4];
    const float* W2  = (const float*)d_in[5];
    const float* b2  = (const float*)d_in[6];
    const float* W3  = (const float*)d_in[7];
    const float* b3  = (const float*)d_in[8];
    const float* Wl  = (const float*)d_in[9];
    const float* bl  = (const float*)d_in[10];
    float* out = (float*)d_out;

    const int N = in_sizes[0] / 512;
    const int E = in_sizes[1] / 2;
    const int Mpad = ((N + 127) / 128) * 128;   // 50048
    const int* src = ei;
    const int* dst = ei + E;

    char* w = (char*)d_ws;
    auto alloc = [&](size_t bytes) {
        char* p = w;
        w += (bytes + 255) & ~(size_t)255;
        return p;
    };
    ushort* Xb        = (ushort*)alloc((size_t)Mpad * 512 * 2);     // bf16 x
    unsigned char* G1 = (unsigned char*)alloc((size_t)Mpad * 256);  // fp8 gemm1 out
    unsigned char* G2 = (unsigned char*)alloc((size_t)Mpad * 128);  // fp8 k5 out
    unsigned char* G3 = (unsigned char*)alloc((size_t)Mpad * 64);   // fp8 k6 out
    ushort* H3   = (ushort*)alloc((size_t)Mpad * 64 * 2);           // bf16 agg3 out
    ushort* Wt1  = (ushort*)alloc(256 * 512 * 2);
    ushort* Wt2  = (ushort*)alloc(128 * 256 * 2);
    ushort* Wt3  = (ushort*)alloc(64 * 128 * 2);
    float* dinv  = (float*)alloc((size_t)Mpad * 4);
    int* rowptr  = (int*)alloc((size_t)(N + 1) * 4);
    int* cursor8 = (int*)alloc((size_t)8 * Mpad * 4);
    int* col     = (int*)alloc((size_t)(E + 16) * 4);
    int* part    = (int*)alloc(256 * 4);
    int nzero = 8 * Mpad + 64 * 64 + 64;        // indeg8 + sums + cnt
    int* indeg8  = (int*)alloc((size_t)nzero * 4);
    float* sums  = (float*)(indeg8 + 8 * Mpad);
    float* cnt   = sums + 64 * 64;

    // k0: zero indeg8 + sums + cnt
    zero_k<<<(nzero + 255) / 256, 256, 0, stream>>>(indeg8, nzero);

    // k1: conv_x ∥ weights ∥ count (interleaved: every 9th block = count)
    int nxblk = (Mpad * 128) / 256;             // conv_x blocks (t = float4 index)
    int ncblk = (E + 255) / 256;                // 3125 count/fill edge-blocks
    int others = nxblk + 672;
    int T = (others * 9) / 8 + 9;               // enough slots for both roles
    prep<<<T, 256, 0, stream>>>(x, Xb, W1, Wt1, W2, Wt2, W3, Wt3,
                                dst, indeg8, N, Mpad, E, nxblk, ncblk);

    // CSR scan
    int nb = (N + 1023) / 1024;
    scan1<<<nb, 1024, 0, stream>>>(indeg8, rowptr, part, N, Mpad);
    scan23<<<(Mpad + 255) / 256, 256, 0, stream>>>(indeg8, rowptr, cursor8, part, dinv,
                                                   N, Mpad, E, nb);

    // fill_csr (8-sliced cursors; same edge-block->copy mapping as count)
    fill_csr<<<ncblk, 256, 0, stream>>>(src, dst, cursor8, col, E, Mpad);

    // gemm1 (512->256), fp8 out
    gemm1<<<(Mpad / 128) * 2, 256, 0, stream>>>(Xb, Wt1, dinv, G1);

    // k5: agg1 (relu, b1) + gemm2 (256->128) fused, BM=64, fp8 gather
    agg_gemm<256, 128><<<Mpad / 64, 512, 0, stream>>>(G1, rowptr, col, dinv, b1,
                                                      Wt2, G2, N, N);
    // k6: agg2 (relu, b2) + gemm3 (128->64) fused, BM=64, fp8 gather
    agg_gemm<128, 64><<<Mpad / 64, 512, 0, stream>>>(G2, rowptr, col, dinv, b2,
                                                     Wt3, G3, N, N);
    // agg3 (b3, no relu), fp8 gather -> bf16 H3
    agg3_f8<<<Mpad / 4, 256, 0, stream>>>(G3, rowptr, col, dinv, b3, H3,
                                          N, Mpad, N);

    pool_sorted<<<(N + 255) / 256, 256, 0, stream>>>(H3, bat, sums, cnt, N);
    final_lin<<<1, 128, 0, stream>>>(sums, cnt, Wl, bl, out);
}